// Round 8
// baseline (537.451 us; speedup 1.0000x reference)
//
#include <hip/hip_runtime.h>
#include <hip/hip_fp16.h>

typedef _Float16 half8 __attribute__((ext_vector_type(8)));
typedef _Float16 half4v __attribute__((ext_vector_type(4)));
typedef float float16v __attribute__((ext_vector_type(16)));

// ---------------- async global->LDS (16B per lane) ----------------
__device__ __forceinline__ void load_lds16(const void* g, void* l) {
    __builtin_amdgcn_global_load_lds(
        (const __attribute__((address_space(1))) void*)g,
        (__attribute__((address_space(3))) void*)l,
        16, 0, 0);
}

// Stage one 128x64 fp16 half-tile (16 KiB) into LDS. LDS dest is linear
// (global_load_lds requirement); the SOURCE slot is XOR-pre-swizzled
// (slot ^= row&7) so a swizzled reader sees natural data (Guideline 21).
__device__ __forceinline__ void stage_half(const _Float16* g, long ld, _Float16* dst) {
    const int t = threadIdx.x;  // 512 threads x 2 chunks x 16B
#pragma unroll
    for (int j = 0; j < 2; ++j) {
        const int c = j * 512 + t;             // 0..1023
        const int row = c >> 3;                // 0..127
        const int slot = (c & 7) ^ (row & 7);  // pre-swizzled source slot
        load_lds16(g + (long)row * ld + slot * 8, dst + c * 8);
    }
}

// ---------------- 256x256 gemm_bt core (32x32x16 f16 MFMA) ----------------
// C[m,n] += sum_k A[m,k]*B[n,k]. BM=BN=256, BK=64, 512 threads = 8 waves
// (2M x 4N); per-wave 128x64 = 4x2 tiles of 32x32, K-tile = 4 ksteps of 16.
// 32 MFMA + 24 ds_read_b128 per wave per K-tile (same reads as 16x16 core,
// half the MFMA instructions, +11% matrix rate: m23 2178 vs m64 1955 TF).
// Fragment layout (mirrors verified 16x16 pattern): A/B lane l -> row l&31,
// k = (l>>5)*8 + j (16B contiguous). One barrier per tile; counted lgkmcnt
// (12 khalf0 reads | 12 khalf1 reads; lgkmcnt(12) -> 16 MFMA; lgkmcnt(0)
// -> 16 MFMA). vmcnt(0) drain at tile end. No setprio (hurts lockstep).
__device__ __forceinline__ void gemm256_core(const _Float16* A, long lda,
                                             const _Float16* B, long ldb,
                                             int K, float16v acc[4][2],
                                             _Float16* lds) {
    const int lane = threadIdx.x & 63;
    const int w    = threadIdx.x >> 6;   // 0..7
    const int wr   = w >> 2;             // 0..1
    const int wc   = w & 3;              // 0..3
    const int rsel = lane & 31;          // row within 32x32 tile
    const int gsel = lane >> 5;          // k-group (0/1) -> 8 f16
    const int NT = K >> 6;

#define STAGE(BUF, KT)                                                             \
    stage_half(A + (KT) * 64, lda, lds + (BUF) * 32768);                           \
    stage_half(A + (long)128 * lda + (KT) * 64, lda, lds + (BUF) * 32768 + 8192);  \
    stage_half(B + (KT) * 64, ldb, lds + (BUF) * 32768 + 16384);                   \
    stage_half(B + (long)128 * ldb + (KT) * 64, ldb, lds + (BUF) * 32768 + 24576);
// read A frag for m-tile MI, kstep KS: row = MI*32+rsel, k = KS*16+gsel*8
#define READ_A1(dst, AH, MI, KS)                                                   \
    {                                                                              \
        const int r = (MI) * 32 + rsel;                                            \
        const int sl = (2 * (KS) + gsel) ^ (r & 7);                                \
        dst = *(const half8*)&(AH)[r * 64 + (sl << 3)];                            \
    }
#define READ_B1(dst, BH, NI, KS)                                                   \
    {                                                                              \
        const int rn = (wc & 1) * 64 + (NI) * 32 + rsel;                           \
        const int sl = (2 * (KS) + gsel) ^ (rn & 7);                               \
        dst = *(const half8*)&(BH)[rn * 64 + (sl << 3)];                           \
    }
// one k-half (2 ksteps): 4mi x 2ni x 2ks = 16 MFMA
#define MFMA_HALF(KH, A_, B_)                                                      \
    _Pragma("unroll") for (int mi = 0; mi < 4; ++mi)                               \
    _Pragma("unroll") for (int ni = 0; ni < 2; ++ni) {                             \
        acc[mi][ni] = __builtin_amdgcn_mfma_f32_32x32x16_f16(                      \
            A_[mi][0], B_[ni][0], acc[mi][ni], 0, 0, 0);                           \
        acc[mi][ni] = __builtin_amdgcn_mfma_f32_32x32x16_f16(                      \
            A_[mi][1], B_[ni][1], acc[mi][ni], 0, 0, 0);                           \
    }
#define SB0 __builtin_amdgcn_sched_barrier(0)

    half8 a0[4][2], a1[4][2], b0[2][2], b1[2][2];

    // prologue: stage tile 0, drain, rendezvous
    STAGE(0, 0);
    asm volatile("s_waitcnt vmcnt(0)" ::: "memory");
    __builtin_amdgcn_s_barrier();
    SB0;

#pragma unroll 1
    for (int t = 0; t < NT; ++t) {
        const int buf = t & 1;
        if (t + 1 < NT) { STAGE(buf ^ 1, t + 1); }
        const _Float16* Ah = lds + buf * 32768 + wr * 8192;
        const _Float16* Bh = lds + buf * 32768 + 16384 + (wc >> 1) * 8192;
        // khalf0 reads (12): A ks0,1 + B ks0,1
#pragma unroll
        for (int mi = 0; mi < 4; ++mi) {
            READ_A1(a0[mi][0], Ah, mi, 0);
            READ_A1(a0[mi][1], Ah, mi, 1);
        }
#pragma unroll
        for (int ni = 0; ni < 2; ++ni) {
            READ_B1(b0[ni][0], Bh, ni, 0);
            READ_B1(b0[ni][1], Bh, ni, 1);
        }
        SB0;
        // khalf1 reads (12): A ks2,3 + B ks2,3
#pragma unroll
        for (int mi = 0; mi < 4; ++mi) {
            READ_A1(a1[mi][0], Ah, mi, 2);
            READ_A1(a1[mi][1], Ah, mi, 3);
        }
#pragma unroll
        for (int ni = 0; ni < 2; ++ni) {
            READ_B1(b1[ni][0], Bh, ni, 2);
            READ_B1(b1[ni][1], Bh, ni, 3);
        }
        // khalf0's 12 reads done; khalf1's 12 still in flight under MFMAs
        asm volatile("s_waitcnt lgkmcnt(12)" ::: "memory");
        SB0;
        MFMA_HALF(0, a0, b0);
        asm volatile("s_waitcnt lgkmcnt(0)" ::: "memory");
        SB0;
        MFMA_HALF(1, a1, b1);
        // own stage loads (issued a full tile ago) must land before rendezvous
        asm volatile("s_waitcnt vmcnt(0)" ::: "memory");
        __builtin_amdgcn_s_barrier();
        SB0;
    }
#undef STAGE
#undef READ_A1
#undef READ_B1
#undef MFMA_HALF
#undef SB0
}

__device__ __forceinline__ void zero_acc(float16v acc[4][2]) {
#pragma unroll
    for (int m = 0; m < 4; ++m)
#pragma unroll
        for (int n = 0; n < 2; ++n)
#pragma unroll
            for (int j = 0; j < 16; ++j) acc[m][n][j] = 0.f;
}

// C/D layout 32x32 (guide-verified): col = lane&31,
// row = (reg&3) + 8*(reg>>2) + 4*(lane>>5);  reg = q*4+j -> row = q*8 + 4*hi + j
// ---------------- kernels ----------------

// merged prep: blocks [0,16384) build X fp16 [16384][1024] from concat;
// blocks [16384,20480) convert Wq,Wk,Wv,Wf fp32 -> Wh fp16 [4][1024][1024]
__global__ __launch_bounds__(256) void prep_kernel(const float* e1, const float* e2,
                                                   const float* e3, const float* Wq,
                                                   const float* Wk, const float* Wv,
                                                   const float* Wf, _Float16* X,
                                                   _Float16* Wdst) {
    const int bid = blockIdx.x;
    if (bid < 16384) {
        long i = ((long)bid * 256 + threadIdx.x) * 4;  // < 16384*1024
        int m = (int)(i >> 10);
        int c = (int)(i & 1023);
        const float* src;
        if (c < 256)      src = e1 + (long)m * 256 + c;
        else if (c < 512) src = e2 + (long)m * 256 + (c - 256);
        else              src = e3 + (long)m * 512 + (c - 512);
        float4 f = *(const float4*)src;
        half4v h;
        h[0] = (_Float16)f.x; h[1] = (_Float16)f.y;
        h[2] = (_Float16)f.z; h[3] = (_Float16)f.w;
        *(half4v*)&X[i] = h;
    } else {
        long i = ((long)(bid - 16384) * 256 + threadIdx.x) * 4;  // < 4*1048576
        int which = (int)(i >> 20);
        long off = i & 1048575;
        const float* w = which == 0 ? Wq : which == 1 ? Wk : which == 2 ? Wv : Wf;
        float4 f = *(const float4*)(w + off);
        half4v h;
        h[0] = (_Float16)f.x; h[1] = (_Float16)f.y;
        h[2] = (_Float16)f.z; h[3] = (_Float16)f.w;
        *(half4v*)&Wdst[i] = h;
    }
}

// QKV projection: z=0 -> q, z=1 -> k (row-major [16384][1024]),
// z=2 -> v written TRANSPOSED as vT [1024][16384] via LDS transpose.
__global__ __launch_bounds__(512, 2) void qkv_kernel(const _Float16* X, const _Float16* W,
                                                     const float* bq, const float* bk,
                                                     const float* bv, _Float16* q,
                                                     _Float16* k, _Float16* vT) {
    extern __shared__ _Float16 lds[];
    const int m0 = blockIdx.x * 256;
    const int n0 = blockIdx.y * 256;
    const int z  = blockIdx.z;
    float16v acc[4][2];
    zero_acc(acc);
    gemm256_core(X + (long)m0 * 1024, 1024,
                 W + (long)z * 1048576 + (long)n0 * 1024, 1024, 1024, acc, lds);

    const float* bias = (z == 0) ? bq : (z == 1) ? bk : bv;
    const int lane = threadIdx.x & 63;
    const int w = threadIdx.x >> 6;
    const int wr = w >> 2, wc = w & 3;
    const int csel = lane & 31;      // output col within 32x32 tile
    const int hi   = lane >> 5;      // row offset 4*hi

    if (z == 2) {
        // ---- bias + fp16 cvt into LDS [c][r], XOR-swizzled r to spread banks
#pragma unroll
        for (int mi = 0; mi < 4; ++mi) {
#pragma unroll
            for (int ni = 0; ni < 2; ++ni) {
                const int c = wc * 64 + ni * 32 + csel;
                const float bb = bias[n0 + c];
#pragma unroll
                for (int qd = 0; qd < 4; ++qd) {
                    const int r = wr * 128 + mi * 32 + qd * 8 + hi * 4;
                    half4v vv;
#pragma unroll
                    for (int j = 0; j < 4; ++j)
                        vv[j] = (_Float16)(acc[mi][ni][qd * 4 + j] + bb);
                    *(half4v*)&lds[c * 256 + (r ^ ((c & 7) << 3))] = vv;
                }
            }
        }
        __syncthreads();
        // ---- write vT rows: 256 cols x 32 chunks of 16B, contiguous in m
#pragma unroll
        for (int it = 0; it < 16; ++it) {
            const int idx = it * 512 + threadIdx.x;  // 0..8191
            const int c = idx >> 5;                  // 0..255
            const int mc = idx & 31;                 // 16B chunk
            half8 v = *(const half8*)&lds[c * 256 + ((mc * 8) ^ ((c & 7) << 3))];
            *(half8*)&vT[(long)(n0 + c) * 16384 + m0 + mc * 8] = v;
        }
    } else {
        _Float16* dst = (z == 0) ? q : k;
#pragma unroll
        for (int mi = 0; mi < 4; ++mi) {
#pragma unroll
            for (int ni = 0; ni < 2; ++ni) {
                const int c = n0 + wc * 64 + ni * 32 + csel;
                const float bb = bias[c];
#pragma unroll
                for (int qd = 0; qd < 4; ++qd) {
                    const int r = m0 + wr * 128 + mi * 32 + qd * 8 + hi * 4;
#pragma unroll
                    for (int j = 0; j < 4; ++j)
                        dst[(long)(r + j) * 1024 + c] =
                            (_Float16)(acc[mi][ni][qd * 4 + j] + bb);
                }
            }
        }
    }
}

// scores[b] = q[b] @ k[b]^T  (fp32 out, chunk-local batch index bz)
__global__ __launch_bounds__(512, 2) void scores_kernel(const _Float16* qh,
                                                        const _Float16* kh, float* scores,
                                                        int b0) {
    extern __shared__ _Float16 lds[];
    const int m0 = blockIdx.x * 256;
    const int n0 = blockIdx.y * 256;
    const int bz = blockIdx.z;
    const int batch = b0 + bz;
    float* C = scores + (long)bz * 2048 * 2048;
    float16v acc[4][2];
    zero_acc(acc);
    gemm256_core(qh + ((long)batch * 2048 + m0) * 1024, 1024,
                 kh + ((long)batch * 2048 + n0) * 1024, 1024, 1024, acc, lds);

    const int lane = threadIdx.x & 63;
    const int w = threadIdx.x >> 6;
    const int wr = w >> 2, wc = w & 3;
    const int csel = lane & 31, hi = lane >> 5;
#pragma unroll
    for (int mi = 0; mi < 4; ++mi) {
#pragma unroll
        for (int ni = 0; ni < 2; ++ni) {
            const int c = n0 + wc * 64 + ni * 32 + csel;
#pragma unroll
            for (int qd = 0; qd < 4; ++qd) {
                const int r = m0 + wr * 128 + mi * 32 + qd * 8 + hi * 4;
#pragma unroll
                for (int j = 0; j < 4; ++j)
                    C[(long)(r + j) * 2048 + c] = acc[mi][ni][qd * 4 + j];
            }
        }
    }
}

// row softmax over 2048 fp32 scores -> fp16 probs. one block per row.
__global__ __launch_bounds__(256) void softmax_kernel(const float* scores,
                                                      _Float16* probs, int b0) {
    const int row = blockIdx.x;
    const int bz  = blockIdx.y;
    const float* s = scores + ((long)bz * 2048 + row) * 2048;
    _Float16* p = probs + ((long)(b0 + bz) * 2048 + row) * 2048;
    const int t = threadIdx.x;

    float4 x0 = ((const float4*)s)[t * 2];
    float4 x1 = ((const float4*)s)[t * 2 + 1];
    float v[8] = {x0.x, x0.y, x0.z, x0.w, x1.x, x1.y, x1.z, x1.w};

    float mx = v[0];
#pragma unroll
    for (int j = 1; j < 8; ++j) mx = fmaxf(mx, v[j]);
#pragma unroll
    for (int d = 1; d < 64; d <<= 1) mx = fmaxf(mx, __shfl_xor(mx, d));
    __shared__ float smax[4];
    __shared__ float ssum[4];
    if ((t & 63) == 0) smax[t >> 6] = mx;
    __syncthreads();
    mx = fmaxf(fmaxf(smax[0], smax[1]), fmaxf(smax[2], smax[3]));

    float e[8];
    float sum = 0.f;
#pragma unroll
    for (int j = 0; j < 8; ++j) {
        e[j] = __expf(v[j] - mx);
        sum += e[j];
    }
#pragma unroll
    for (int d = 1; d < 64; d <<= 1) sum += __shfl_xor(sum, d);
    if ((t & 63) == 0) ssum[t >> 6] = sum;
    __syncthreads();
    sum = ssum[0] + ssum[1] + ssum[2] + ssum[3];
    const float inv = 1.0f / sum;

    half8 o;
#pragma unroll
    for (int j = 0; j < 8; ++j) o[j] = (_Float16)(e[j] * inv);
    *(half8*)&p[t * 8] = o;
}

// weighted[b] = probs[b] @ v[b] via vT (gemm_bt form). fp16 out [16384][1024].
__global__ __launch_bounds__(512, 2) void pv_kernel(const _Float16* probs,
                                                    const _Float16* vT, _Float16* wt) {
    extern __shared__ _Float16 lds[];
    const int m0 = blockIdx.x * 256;
    const int n0 = blockIdx.y * 256;
    const int batch = blockIdx.z;
    float16v acc[4][2];
    zero_acc(acc);
    gemm256_core(probs + ((long)batch * 2048 + m0) * 2048, 2048,
                 vT + (long)n0 * 16384 + (long)batch * 2048, 16384, 2048, acc, lds);

    const int lane = threadIdx.x & 63;
    const int w = threadIdx.x >> 6;
    const int wr = w >> 2, wc = w & 3;
    const int csel = lane & 31, hi = lane >> 5;
#pragma unroll
    for (int mi = 0; mi < 4; ++mi) {
#pragma unroll
        for (int ni = 0; ni < 2; ++ni) {
            const int c = n0 + wc * 64 + ni * 32 + csel;
#pragma unroll
            for (int qd = 0; qd < 4; ++qd) {
                const int r = wr * 128 + mi * 32 + qd * 8 + hi * 4;
#pragma unroll
                for (int j = 0; j < 4; ++j)
                    wt[((long)batch * 2048 + m0 + r + j) * 1024 + c] =
                        (_Float16)acc[mi][ni][qd * 4 + j];
            }
        }
    }
}

// out = leakyrelu(weighted @ Wf^T + bf), fp32 out.
__global__ __launch_bounds__(512, 2) void out_kernel(const _Float16* wt, const _Float16* Wf,
                                                     const float* bf_, float* out) {
    extern __shared__ _Float16 lds[];
    const int m0 = blockIdx.x * 256;
    const int n0 = blockIdx.y * 256;
    float16v acc[4][2];
    zero_acc(acc);
    gemm256_core(wt + (long)m0 * 1024, 1024, Wf + (long)n0 * 1024, 1024, 1024, acc, lds);

    const int lane = threadIdx.x & 63;
    const int w = threadIdx.x >> 6;
    const int wr = w >> 2, wc = w & 3;
    const int csel = lane & 31, hi = lane >> 5;
#pragma unroll
    for (int mi = 0; mi < 4; ++mi) {
#pragma unroll
        for (int ni = 0; ni < 2; ++ni) {
            const int c = n0 + wc * 64 + ni * 32 + csel;
            const float bb = bf_[c];
#pragma unroll
            for (int qd = 0; qd < 4; ++qd) {
                const int r = m0 + wr * 128 + mi * 32 + qd * 8 + hi * 4;
#pragma unroll
                for (int j = 0; j < 4; ++j) {
                    float y = acc[mi][ni][qd * 4 + j] + bb;
                    y = (y >= 0.f) ? y : 0.2f * y;
                    out[(long)(r + j) * 1024 + c] = y;
                }
            }
        }
    }
}

// ---------------- launcher ----------------
extern "C" void kernel_launch(void* const* d_in, const int* in_sizes, int n_in,
                              void* d_out, int out_size, void* d_ws, size_t ws_size,
                              hipStream_t stream) {
    const float* e1 = (const float*)d_in[0];
    const float* e2 = (const float*)d_in[1];
    const float* e3 = (const float*)d_in[2];
    const float* Wq = (const float*)d_in[3];
    const float* bq = (const float*)d_in[4];
    const float* Wk = (const float*)d_in[5];
    const float* bk = (const float*)d_in[6];
    const float* Wv = (const float*)d_in[7];
    const float* bv = (const float*)d_in[8];
    const float* Wf = (const float*)d_in[9];
    const float* bf_ = (const float*)d_in[10];
    float* out = (float*)d_out;

    // raise dynamic-LDS cap to 128 KiB (idempotent; not a stream op)
    const int LDS_BYTES = 131072;
    (void)hipFuncSetAttribute((const void*)qkv_kernel,
                              hipFuncAttributeMaxDynamicSharedMemorySize, LDS_BYTES);
    (void)hipFuncSetAttribute((const void*)scores_kernel,
                              hipFuncAttributeMaxDynamicSharedMemorySize, LDS_BYTES);
    (void)hipFuncSetAttribute((const void*)pv_kernel,
                              hipFuncAttributeMaxDynamicSharedMemorySize, LDS_BYTES);
    (void)hipFuncSetAttribute((const void*)out_kernel,
                              hipFuncAttributeMaxDynamicSharedMemorySize, LDS_BYTES);

    char* ws = (char*)d_ws;
    const size_t MB = 1024 * 1024;
    _Float16* Xh    = (_Float16*)(ws + 0);        // 32 MiB
    _Float16* Wh    = (_Float16*)(ws + 32 * MB);  // 8 MiB [4][1024][1024]
    _Float16* qh    = (_Float16*)(ws + 40 * MB);  // 32 MiB
    _Float16* kh    = (_Float16*)(ws + 72 * MB);  // 32 MiB
    _Float16* vT    = (_Float16*)(ws + 104 * MB); // 32 MiB [1024][16384]
    _Float16* wt    = (_Float16*)(ws + 136 * MB); // 32 MiB
    _Float16* probs = (_Float16*)(ws + 168 * MB); // 64 MiB [8][2048][2048]
    float* scores   = (float*)(ws + 232 * MB);    // NB * 16 MiB scratch

    long nb_max = ((long)ws_size - 232 * (long)MB) / (16 * (long)MB);
    int NB = (int)(nb_max < 1 ? 1 : (nb_max > 8 ? 8 : nb_max));

    prep_kernel<<<20480, 256, 0, stream>>>(e1, e2, e3, Wq, Wk, Wv, Wf, Xh, Wh);
    qkv_kernel<<<dim3(64, 4, 3), 512, LDS_BYTES, stream>>>(Xh, Wh, bq, bk, bv, qh, kh, vT);
    for (int b0 = 0; b0 < 8; b0 += NB) {
        int nb = 8 - b0 < NB ? 8 - b0 : NB;
        scores_kernel<<<dim3(8, 8, nb), 512, LDS_BYTES, stream>>>(qh, kh, scores, b0);
        softmax_kernel<<<dim3(2048, nb), 256, 0, stream>>>(scores, probs, b0);
    }
    pv_kernel<<<dim3(8, 4, 8), 512, LDS_BYTES, stream>>>(probs, vT, wt);
    out_kernel<<<dim3(64, 4), 512, LDS_BYTES, stream>>>(wt, Wh + 3 * 1048576, bf_, out);
}

// Round 9
// 367.878 us; speedup vs baseline: 1.4609x; 1.4609x over previous
//
#include <hip/hip_runtime.h>
#include <hip/hip_fp16.h>

typedef _Float16 half8 __attribute__((ext_vector_type(8)));
typedef _Float16 half4v __attribute__((ext_vector_type(4)));
typedef float floatx4 __attribute__((ext_vector_type(4)));

// ---------------- async global->LDS (16B per lane) ----------------
__device__ __forceinline__ void load_lds16(const void* g, void* l) {
    __builtin_amdgcn_global_load_lds(
        (const __attribute__((address_space(1))) void*)g,
        (__attribute__((address_space(3))) void*)l,
        16, 0, 0);
}

// Stage one 128x64 fp16 half-tile (16 KiB) into LDS. LDS dest linear;
// SOURCE slot XOR-pre-swizzled (slot ^= row&7) -- Guideline 21.
__device__ __forceinline__ void stage_half(const _Float16* g, long ld, _Float16* dst) {
    const int t = threadIdx.x;  // 512 threads x 2 chunks x 16B
#pragma unroll
    for (int j = 0; j < 2; ++j) {
        const int c = j * 512 + t;             // 0..1023
        const int row = c >> 3;                // 0..127
        const int slot = (c & 7) ^ (row & 7);  // pre-swizzled source slot
        load_lds16(g + (long)row * ld + slot * 8, dst + c * 8);
    }
}

#define GEMM_PRELUDE                                                               \
    const int lane = threadIdx.x & 63;                                             \
    const int w    = threadIdx.x >> 6;                                             \
    const int wr   = w >> 2;                                                       \
    const int wc   = w & 3;                                                        \
    const int rsel = lane & 15, gsel = lane >> 4;                                  \
    const int NT = K >> 6;                                                         \
    (void)lane;
#define STAGE(BUF, KT)                                                             \
    stage_half(A + (KT) * 64, lda, lds + (BUF) * 32768);                           \
    stage_half(A + (long)128 * lda + (KT) * 64, lda, lds + (BUF) * 32768 + 8192);  \
    stage_half(B + (KT) * 64, ldb, lds + (BUF) * 32768 + 16384);                   \
    stage_half(B + (long)128 * ldb + (KT) * 64, ldb, lds + (BUF) * 32768 + 24576);
#define READ_A(dst, AH, MH)                                                        \
    _Pragma("unroll") for (int mi = 0; mi < 4; ++mi) {                             \
        const int r = ((MH) * 4 + mi) * 16 + rsel;                                 \
        dst[mi][0] = *(const half8*)&(AH)[r * 64 + ((gsel ^ (r & 7)) << 3)];       \
        dst[mi][1] = *(const half8*)&(AH)[r * 64 + (((4 + gsel) ^ (r & 7)) << 3)]; \
    }
#define READ_B(dst, BH, NH)                                                        \
    _Pragma("unroll") for (int ni = 0; ni < 2; ++ni) {                             \
        const int rn = (wc & 1) * 64 + ((NH) * 2 + ni) * 16 + rsel;                \
        dst[ni][0] = *(const half8*)&(BH)[rn * 64 + ((gsel ^ (rn & 7)) << 3)];     \
        dst[ni][1] = *(const half8*)&(BH)[rn * 64 + (((4 + gsel) ^ (rn & 7)) << 3)]; \
    }
#define MFMA_Q(MH, NH, A_, B_)                                                     \
    _Pragma("unroll") for (int mi = 0; mi < 4; ++mi)                               \
    _Pragma("unroll") for (int ni = 0; ni < 2; ++ni) {                             \
        acc[(MH) * 4 + mi][(NH) * 2 + ni] = __builtin_amdgcn_mfma_f32_16x16x32_f16( \
            A_[mi][0], B_[ni][0], acc[(MH) * 4 + mi][(NH) * 2 + ni], 0, 0, 0);     \
        acc[(MH) * 4 + mi][(NH) * 2 + ni] = __builtin_amdgcn_mfma_f32_16x16x32_f16( \
            A_[mi][1], B_[ni][1], acc[(MH) * 4 + mi][(NH) * 2 + ni], 0, 0, 0);     \
    }
#define SB0 __builtin_amdgcn_sched_barrier(0)

// ---------------- 256x256 gemm_bt core (R7-verified: 42% MfmaUtil) ----------
__device__ __forceinline__ void gemm256_core(const _Float16* A, long lda,
                                             const _Float16* B, long ldb,
                                             int K, floatx4 acc[8][4],
                                             _Float16* lds) {
    GEMM_PRELUDE
    half8 a_lo[4][2], a_hi[4][2], b_lo[2][2], b_hi[2][2];
    STAGE(0, 0);
    asm volatile("s_waitcnt vmcnt(0)" ::: "memory");
    __builtin_amdgcn_s_barrier();
    SB0;
#pragma unroll 1
    for (int t = 0; t < NT; ++t) {
        const int buf = t & 1;
        if (t + 1 < NT) { STAGE(buf ^ 1, t + 1); }
        const _Float16* Ah = lds + buf * 32768 + wr * 8192;
        const _Float16* Bh = lds + buf * 32768 + 16384 + (wc >> 1) * 8192;
        READ_A(a_lo, Ah, 0);
        READ_B(b_lo, Bh, 0);
        SB0;
        READ_A(a_hi, Ah, 1);
        SB0;
        READ_B(b_hi, Bh, 1);
        asm volatile("s_waitcnt lgkmcnt(12)" ::: "memory");
        SB0;
        MFMA_Q(0, 0, a_lo, b_lo);
        asm volatile("s_waitcnt lgkmcnt(4)" ::: "memory");
        SB0;
        MFMA_Q(1, 0, a_hi, b_lo);
        asm volatile("s_waitcnt lgkmcnt(0)" ::: "memory");
        SB0;
        MFMA_Q(0, 1, a_lo, b_hi);
        MFMA_Q(1, 1, a_hi, b_hi);
        asm volatile("s_waitcnt vmcnt(0)" ::: "memory");
        __builtin_amdgcn_s_barrier();
        SB0;
    }
}

// ---------------- pv variant: per-row fp16 A-scaling from LDS table --------
// scl = LDS float[8][256]: scale[kv_tile][q_row_local]. FIFO per tile:
// scl(8) | a_lo+b_lo(12) | a_hi(8) | b_hi(4) = 32 lgkm ops ->
// lgkmcnt(12) covers scl+a_lo+b_lo; (4) covers a_hi; (0) all.
__device__ __forceinline__ void gemm256_core_pv(const _Float16* A, long lda,
                                                const _Float16* B, long ldb,
                                                int K, floatx4 acc[8][4],
                                                _Float16* lds, const float* scl) {
    GEMM_PRELUDE
    half8 a_lo[4][2], a_hi[4][2], b_lo[2][2], b_hi[2][2];
    STAGE(0, 0);
    asm volatile("s_waitcnt vmcnt(0)" ::: "memory");
    __builtin_amdgcn_s_barrier();
    SB0;
#pragma unroll 1
    for (int t = 0; t < NT; ++t) {
        const int buf = t & 1;
        if (t + 1 < NT) { STAGE(buf ^ 1, t + 1); }
        const _Float16* Ah = lds + buf * 32768 + wr * 8192;
        const _Float16* Bh = lds + buf * 32768 + 16384 + (wc >> 1) * 8192;
        // scale row-vector for this kv tile (t>>2): 8 ds_read_b32 first
        const float* srow = scl + (t >> 2) * 256 + wr * 128 + rsel;
        float s_lo[4], s_hi[4];
#pragma unroll
        for (int mi = 0; mi < 4; ++mi) s_lo[mi] = srow[mi * 16];
#pragma unroll
        for (int mi = 0; mi < 4; ++mi) s_hi[mi] = srow[64 + mi * 16];
        SB0;
        READ_A(a_lo, Ah, 0);
        READ_B(b_lo, Bh, 0);
        SB0;
        READ_A(a_hi, Ah, 1);
        SB0;
        READ_B(b_hi, Bh, 1);
        asm volatile("s_waitcnt lgkmcnt(12)" ::: "memory");
        SB0;
#pragma unroll
        for (int mi = 0; mi < 4; ++mi) {
            const _Float16 h = (_Float16)s_lo[mi];
            a_lo[mi][0] = a_lo[mi][0] * h;
            a_lo[mi][1] = a_lo[mi][1] * h;
        }
        MFMA_Q(0, 0, a_lo, b_lo);
        asm volatile("s_waitcnt lgkmcnt(4)" ::: "memory");
        SB0;
#pragma unroll
        for (int mi = 0; mi < 4; ++mi) {
            const _Float16 h = (_Float16)s_hi[mi];
            a_hi[mi][0] = a_hi[mi][0] * h;
            a_hi[mi][1] = a_hi[mi][1] * h;
        }
        MFMA_Q(1, 0, a_hi, b_lo);
        asm volatile("s_waitcnt lgkmcnt(0)" ::: "memory");
        SB0;
        MFMA_Q(0, 1, a_lo, b_hi);
        MFMA_Q(1, 1, a_hi, b_hi);
        asm volatile("s_waitcnt vmcnt(0)" ::: "memory");
        __builtin_amdgcn_s_barrier();
        SB0;
    }
}

__device__ __forceinline__ void zero_acc8(floatx4 acc[8][4]) {
    const floatx4 z = {0.f, 0.f, 0.f, 0.f};
#pragma unroll
    for (int m = 0; m < 8; ++m)
#pragma unroll
        for (int n = 0; n < 4; ++n) acc[m][n] = z;
}

// ---------------- kernels ----------------

// merged prep: blocks [0,16384) build X fp16; [16384,20480) convert weights.
__global__ __launch_bounds__(256) void prep_kernel(const float* e1, const float* e2,
                                                   const float* e3, const float* Wq,
                                                   const float* Wk, const float* Wv,
                                                   const float* Wf, _Float16* X,
                                                   _Float16* Wdst) {
    const int bid = blockIdx.x;
    if (bid < 16384) {
        long i = ((long)bid * 256 + threadIdx.x) * 4;
        int m = (int)(i >> 10);
        int c = (int)(i & 1023);
        const float* src;
        if (c < 256)      src = e1 + (long)m * 256 + c;
        else if (c < 512) src = e2 + (long)m * 256 + (c - 256);
        else              src = e3 + (long)m * 512 + (c - 512);
        float4 f = *(const float4*)src;
        half4v h;
        h[0] = (_Float16)f.x; h[1] = (_Float16)f.y;
        h[2] = (_Float16)f.z; h[3] = (_Float16)f.w;
        *(half4v*)&X[i] = h;
    } else {
        long i = ((long)(bid - 16384) * 256 + threadIdx.x) * 4;
        int which = (int)(i >> 20);
        long off = i & 1048575;
        const float* w = which == 0 ? Wq : which == 1 ? Wk : which == 2 ? Wv : Wf;
        float4 f = *(const float4*)(w + off);
        half4v h;
        h[0] = (_Float16)f.x; h[1] = (_Float16)f.y;
        h[2] = (_Float16)f.z; h[3] = (_Float16)f.w;
        *(half4v*)&Wdst[i] = h;
    }
}

// QKV projection: z=0 -> q, z=1 -> k; z=2 -> vT via LDS transpose.
__global__ __launch_bounds__(512, 2) void qkv_kernel(const _Float16* X, const _Float16* W,
                                                     const float* bq, const float* bk,
                                                     const float* bv, _Float16* q,
                                                     _Float16* k, _Float16* vT) {
    extern __shared__ _Float16 lds[];
    const int m0 = blockIdx.x * 256;
    const int n0 = blockIdx.y * 256;
    const int z  = blockIdx.z;
    floatx4 acc[8][4];
    zero_acc8(acc);
    gemm256_core(X + (long)m0 * 1024, 1024,
                 W + (long)z * 1048576 + (long)n0 * 1024, 1024, 1024, acc, lds);

    const float* bias = (z == 0) ? bq : (z == 1) ? bk : bv;
    const int lane = threadIdx.x & 63;
    const int w = threadIdx.x >> 6;
    const int wr = w >> 2, wc = w & 3;
    const int rsel = lane & 15, gsel = lane >> 4;

    if (z == 2) {
        const int rb = wr * 128 + gsel * 4;
        const int cb = wc * 64 + rsel;
#pragma unroll
        for (int mI = 0; mI < 8; ++mI) {
#pragma unroll
            for (int nI = 0; nI < 4; ++nI) {
                const int c = cb + nI * 16;
                const int r = rb + mI * 16;
                const float bb = bias[n0 + c];
                half4v vv;
#pragma unroll
                for (int j = 0; j < 4; ++j) vv[j] = (_Float16)(acc[mI][nI][j] + bb);
                *(half4v*)&lds[c * 256 + (r ^ ((c & 7) << 3))] = vv;
            }
        }
        __syncthreads();
#pragma unroll
        for (int it = 0; it < 16; ++it) {
            const int idx = it * 512 + threadIdx.x;  // 0..8191
            const int c = idx >> 5;
            const int mc = idx & 31;
            half8 v = *(const half8*)&lds[c * 256 + ((mc * 8) ^ ((c & 7) << 3))];
            *(half8*)&vT[(long)(n0 + c) * 16384 + m0 + mc * 8] = v;
        }
    } else {
        _Float16* dst = (z == 0) ? q : k;
        const int r0 = m0 + wr * 128 + gsel * 4;
        const int c0 = n0 + wc * 64 + rsel;
#pragma unroll
        for (int mI = 0; mI < 8; ++mI) {
#pragma unroll
            for (int nI = 0; nI < 4; ++nI) {
                const int r = r0 + mI * 16;
                const int c = c0 + nI * 16;
                const float bb = bias[c];
#pragma unroll
                for (int j = 0; j < 4; ++j)
                    dst[(long)(r + j) * 1024 + c] = (_Float16)(acc[mI][nI][j] + bb);
            }
        }
    }
}

// scores + partial softmax: es[b,q,kv] = exp(q.k - rowtilemax) fp16;
// tmax/tsum[b][tile][row] fp32 partials for the cross-tile reduce.
__global__ __launch_bounds__(512, 2) void scores_kernel(const _Float16* qh,
                                                        const _Float16* kh,
                                                        _Float16* es, float* tmax,
                                                        float* tsum) {
    extern __shared__ _Float16 lds[];
    const int m0 = blockIdx.x * 256;
    const int n0 = blockIdx.y * 256;   // = tile * 256
    const int tile = blockIdx.y;
    const int b = blockIdx.z;
    floatx4 acc[8][4];
    zero_acc8(acc);
    gemm256_core(qh + ((long)b * 2048 + m0) * 1024, 1024,
                 kh + ((long)b * 2048 + n0) * 1024, 1024, 1024, acc, lds);

    const int lane = threadIdx.x & 63;
    const int w = threadIdx.x >> 6;
    const int wr = w >> 2, wc = w & 3;
    const int rsel = lane & 15, gsel = lane >> 4;
    float* red = (float*)lds;  // [256][4]

    // ---- per-(row, tile) max: over n (reg) -> rsel (shfl) -> wc (LDS)
    float mx[8][4];
#pragma unroll
    for (int m = 0; m < 8; ++m)
#pragma unroll
        for (int j = 0; j < 4; ++j) {
            float v = acc[m][0][j];
#pragma unroll
            for (int n = 1; n < 4; ++n) v = fmaxf(v, acc[m][n][j]);
#pragma unroll
            for (int d = 1; d < 16; d <<= 1) v = fmaxf(v, __shfl_xor(v, d));
            mx[m][j] = v;
        }
    if (rsel == 0) {
#pragma unroll
        for (int m = 0; m < 8; ++m)
#pragma unroll
            for (int j = 0; j < 4; ++j)
                red[(wr * 128 + m * 16 + gsel * 4 + j) * 4 + wc] = mx[m][j];
    }
    __syncthreads();
#pragma unroll
    for (int m = 0; m < 8; ++m)
#pragma unroll
        for (int j = 0; j < 4; ++j) {
            const int row = wr * 128 + m * 16 + gsel * 4 + j;
            float4 rv = *(const float4*)&red[row * 4];
            mx[m][j] = fmaxf(fmaxf(rv.x, rv.y), fmaxf(rv.z, rv.w));
        }
    __syncthreads();  // all reads done before red reuse

    // ---- exp in place + per-(row, tile) sum
    float sm[8][4];
#pragma unroll
    for (int m = 0; m < 8; ++m)
#pragma unroll
        for (int j = 0; j < 4; ++j) {
            float s = 0.f;
#pragma unroll
            for (int n = 0; n < 4; ++n) {
                float e = __expf(acc[m][n][j] - mx[m][j]);
                acc[m][n][j] = e;
                s += e;
            }
#pragma unroll
            for (int d = 1; d < 16; d <<= 1) s += __shfl_xor(s, d);
            sm[m][j] = s;
        }
    if (rsel == 0) {
#pragma unroll
        for (int m = 0; m < 8; ++m)
#pragma unroll
            for (int j = 0; j < 4; ++j)
                red[(wr * 128 + m * 16 + gsel * 4 + j) * 4 + wc] = sm[m][j];
    }
    __syncthreads();
    if (wc == 0 && rsel == 0) {
        const long base = ((long)b * 8 + tile) * 2048 + m0;
#pragma unroll
        for (int m = 0; m < 8; ++m)
#pragma unroll
            for (int j = 0; j < 4; ++j) {
                const int row = wr * 128 + m * 16 + gsel * 4 + j;
                float4 rv = *(const float4*)&red[row * 4];
                tmax[base + row] = mx[m][j];
                tsum[base + row] = rv.x + rv.y + rv.z + rv.w;
            }
    }
    // ---- store exp-scores fp16
    const long rbase = (long)b * 2048 * 2048;
    const int r0 = m0 + wr * 128 + gsel * 4;
    const int c0 = n0 + wc * 64 + rsel;
#pragma unroll
    for (int m = 0; m < 8; ++m)
#pragma unroll
        for (int n = 0; n < 4; ++n)
#pragma unroll
            for (int j = 0; j < 4; ++j)
                es[rbase + (long)(r0 + m * 16 + j) * 2048 + c0 + n * 16] =
                    (_Float16)acc[m][n][j];
}

// cross-tile softmax reduce: scale[b][t][row] = exp(m_t - m_g) / Z
__global__ __launch_bounds__(256) void sm_reduce_kernel(const float* tmax,
                                                        const float* tsum,
                                                        float* scale) {
    const int idx = blockIdx.x * 256 + threadIdx.x;  // < 8*2048
    const int b = idx >> 11, row = idx & 2047;
    const float* mrow = tmax + (long)b * 8 * 2048 + row;
    const float* srow = tsum + (long)b * 8 * 2048 + row;
    float m[8];
    float mg = -1e30f;
#pragma unroll
    for (int t = 0; t < 8; ++t) {
        m[t] = mrow[(long)t * 2048];
        mg = fmaxf(mg, m[t]);
    }
    float Z = 0.f;
#pragma unroll
    for (int t = 0; t < 8; ++t) Z += srow[(long)t * 2048] * __expf(m[t] - mg);
    const float inv = 1.0f / Z;
    float* orow = scale + (long)b * 8 * 2048 + row;
#pragma unroll
    for (int t = 0; t < 8; ++t) orow[(long)t * 2048] = __expf(m[t] - mg) * inv;
}

// weighted[b] = (es * scale)[b] @ v[b] via vT. fp16 out [16384][1024].
__global__ __launch_bounds__(512, 2) void pv_kernel(const _Float16* es,
                                                    const _Float16* vT,
                                                    const float* scale_g,
                                                    _Float16* wt) {
    extern __shared__ _Float16 lds[];
    const int m0 = blockIdx.x * 256;
    const int n0 = blockIdx.y * 256;
    const int batch = blockIdx.z;
    // stage scale[8 tiles][256 rows] into LDS after the 128KB dbuf
    float* scl = (float*)(lds + 65536);
    for (int i = threadIdx.x; i < 2048; i += 512) {
        const int t8 = i >> 8, rl = i & 255;
        scl[i] = scale_g[((long)batch * 8 + t8) * 2048 + m0 + rl];
    }
    __syncthreads();
    floatx4 acc[8][4];
    zero_acc8(acc);
    gemm256_core_pv(es + ((long)batch * 2048 + m0) * 2048, 2048,
                    vT + (long)n0 * 16384 + (long)batch * 2048, 16384, 2048, acc,
                    lds, scl);

    const int lane = threadIdx.x & 63;
    const int w = threadIdx.x >> 6;
    const int wr = w >> 2, wc = w & 3;
    const int r0 = wr * 128 + (lane >> 4) * 4;
    const int c0 = n0 + wc * 64 + (lane & 15);
#pragma unroll
    for (int m = 0; m < 8; ++m) {
#pragma unroll
        for (int n = 0; n < 4; ++n) {
            const int r = r0 + m * 16;
            const int c = c0 + n * 16;
#pragma unroll
            for (int j = 0; j < 4; ++j)
                wt[((long)batch * 2048 + m0 + r + j) * 1024 + c] =
                    (_Float16)acc[m][n][j];
        }
    }
}

// out = leakyrelu(weighted @ Wf^T + bf), fp32 out.
__global__ __launch_bounds__(512, 2) void out_kernel(const _Float16* wt, const _Float16* Wf,
                                                     const float* bf_, float* out) {
    extern __shared__ _Float16 lds[];
    const int m0 = blockIdx.x * 256;
    const int n0 = blockIdx.y * 256;
    floatx4 acc[8][4];
    zero_acc8(acc);
    gemm256_core(wt + (long)m0 * 1024, 1024, Wf + (long)n0 * 1024, 1024, 1024, acc, lds);

    const int lane = threadIdx.x & 63;
    const int w = threadIdx.x >> 6;
    const int wr = w >> 2, wc = w & 3;
    const int r0 = m0 + wr * 128 + (lane >> 4) * 4;
    const int c0 = n0 + wc * 64 + (lane & 15);
#pragma unroll
    for (int m = 0; m < 8; ++m) {
#pragma unroll
        for (int n = 0; n < 4; ++n) {
            const int r = r0 + m * 16;
            const int c = c0 + n * 16;
            const float bb = bf_[c];
#pragma unroll
            for (int j = 0; j < 4; ++j) {
                float y = acc[m][n][j] + bb;
                y = (y >= 0.f) ? y : 0.2f * y;
                out[(long)(r + j) * 1024 + c] = y;
            }
        }
    }
}

// ---------------- launcher ----------------
extern "C" void kernel_launch(void* const* d_in, const int* in_sizes, int n_in,
                              void* d_out, int out_size, void* d_ws, size_t ws_size,
                              hipStream_t stream) {
    const float* e1 = (const float*)d_in[0];
    const float* e2 = (const float*)d_in[1];
    const float* e3 = (const float*)d_in[2];
    const float* Wq = (const float*)d_in[3];
    const float* bq = (const float*)d_in[4];
    const float* Wk = (const float*)d_in[5];
    const float* bk = (const float*)d_in[6];
    const float* Wv = (const float*)d_in[7];
    const float* bv = (const float*)d_in[8];
    const float* Wf = (const float*)d_in[9];
    const float* bf_ = (const float*)d_in[10];
    float* out = (float*)d_out;

    const int LDS_BYTES = 131072;
    const int LDS_PV = 131072 + 8192;
    (void)hipFuncSetAttribute((const void*)qkv_kernel,
                              hipFuncAttributeMaxDynamicSharedMemorySize, LDS_BYTES);
    (void)hipFuncSetAttribute((const void*)scores_kernel,
                              hipFuncAttributeMaxDynamicSharedMemorySize, LDS_BYTES);
    (void)hipFuncSetAttribute((const void*)pv_kernel,
                              hipFuncAttributeMaxDynamicSharedMemorySize, LDS_PV);
    (void)hipFuncSetAttribute((const void*)out_kernel,
                              hipFuncAttributeMaxDynamicSharedMemorySize, LDS_BYTES);

    char* ws = (char*)d_ws;
    const size_t MB = 1024 * 1024;
    _Float16* Xh    = (_Float16*)(ws + 0);        // 32 MiB
    _Float16* Wh    = (_Float16*)(ws + 32 * MB);  // 8 MiB
    _Float16* qh    = (_Float16*)(ws + 40 * MB);  // 32 MiB
    _Float16* kh    = (_Float16*)(ws + 72 * MB);  // 32 MiB
    _Float16* vT    = (_Float16*)(ws + 104 * MB); // 32 MiB [1024][16384]
    _Float16* wt    = (_Float16*)(ws + 136 * MB); // 32 MiB
    _Float16* es    = (_Float16*)(ws + 168 * MB); // 64 MiB [8][2048][2048] fp16
    float* tmax     = (float*)(ws + 232 * MB);              // 512 KiB [8][8][2048]
    float* tsum     = (float*)(ws + 232 * MB + 524288);     // 512 KiB
    float* scale    = (float*)(ws + 233 * MB);              // 512 KiB

    prep_kernel<<<20480, 256, 0, stream>>>(e1, e2, e3, Wq, Wk, Wv, Wf, Xh, Wh);
    qkv_kernel<<<dim3(64, 4, 3), 512, LDS_BYTES, stream>>>(Xh, Wh, bq, bk, bv, qh, kh, vT);
    scores_kernel<<<dim3(8, 8, 8), 512, LDS_BYTES, stream>>>(qh, kh, es, tmax, tsum);
    sm_reduce_kernel<<<64, 256, 0, stream>>>(tmax, tsum, scale);
    pv_kernel<<<dim3(8, 4, 8), 512, LDS_PV, stream>>>(es, vT, scale, wt);
    out_kernel<<<dim3(64, 4), 512, LDS_BYTES, stream>>>(wt, Wh + 3 * 1048576, bf_, out);
}

// Round 10
// 363.748 us; speedup vs baseline: 1.4775x; 1.0114x over previous
//
#include <hip/hip_runtime.h>
#include <hip/hip_fp16.h>

typedef _Float16 half8 __attribute__((ext_vector_type(8)));
typedef _Float16 half4v __attribute__((ext_vector_type(4)));
typedef float floatx4 __attribute__((ext_vector_type(4)));

// ---------------- async global->LDS (16B per lane) ----------------
__device__ __forceinline__ void load_lds16(const void* g, void* l) {
    __builtin_amdgcn_global_load_lds(
        (const __attribute__((address_space(1))) void*)g,
        (__attribute__((address_space(3))) void*)l,
        16, 0, 0);
}

// Stage one 128x64 fp16 half-tile (16 KiB) into LDS. LDS dest linear;
// SOURCE slot XOR-pre-swizzled (slot ^= row&7) -- Guideline 21.
__device__ __forceinline__ void stage_half(const _Float16* g, long ld, _Float16* dst) {
    const int t = threadIdx.x;  // 512 threads x 2 chunks x 16B
#pragma unroll
    for (int j = 0; j < 2; ++j) {
        const int c = j * 512 + t;             // 0..1023
        const int row = c >> 3;                // 0..127
        const int slot = (c & 7) ^ (row & 7);  // pre-swizzled source slot
        load_lds16(g + (long)row * ld + slot * 8, dst + c * 8);
    }
}

#define GEMM_PRELUDE                                                               \
    const int lane = threadIdx.x & 63;                                             \
    const int w    = threadIdx.x >> 6;                                             \
    const int wr   = w >> 2;                                                       \
    const int wc   = w & 3;                                                        \
    const int rsel = lane & 15, gsel = lane >> 4;                                  \
    const int NT = K >> 6;                                                         \
    (void)lane;
#define STAGE(BUF, KT)                                                             \
    stage_half(A + (KT) * 64, lda, lds + (BUF) * 32768);                           \
    stage_half(A + (long)128 * lda + (KT) * 64, lda, lds + (BUF) * 32768 + 8192);  \
    stage_half(B + (KT) * 64, ldb, lds + (BUF) * 32768 + 16384);                   \
    stage_half(B + (long)128 * ldb + (KT) * 64, ldb, lds + (BUF) * 32768 + 24576);
#define READ_A(dst, AH, MH)                                                        \
    _Pragma("unroll") for (int mi = 0; mi < 4; ++mi) {                             \
        const int r = ((MH) * 4 + mi) * 16 + rsel;                                 \
        dst[mi][0] = *(const half8*)&(AH)[r * 64 + ((gsel ^ (r & 7)) << 3)];       \
        dst[mi][1] = *(const half8*)&(AH)[r * 64 + (((4 + gsel) ^ (r & 7)) << 3)]; \
    }
#define READ_B(dst, BH, NH)                                                        \
    _Pragma("unroll") for (int ni = 0; ni < 2; ++ni) {                             \
        const int rn = (wc & 1) * 64 + ((NH) * 2 + ni) * 16 + rsel;                \
        dst[ni][0] = *(const half8*)&(BH)[rn * 64 + ((gsel ^ (rn & 7)) << 3)];     \
        dst[ni][1] = *(const half8*)&(BH)[rn * 64 + (((4 + gsel) ^ (rn & 7)) << 3)]; \
    }
#define MFMA_Q(MH, NH, A_, B_)                                                     \
    _Pragma("unroll") for (int mi = 0; mi < 4; ++mi)                               \
    _Pragma("unroll") for (int ni = 0; ni < 2; ++ni) {                             \
        acc[(MH) * 4 + mi][(NH) * 2 + ni] = __builtin_amdgcn_mfma_f32_16x16x32_f16( \
            A_[mi][0], B_[ni][0], acc[(MH) * 4 + mi][(NH) * 2 + ni], 0, 0, 0);     \
        acc[(MH) * 4 + mi][(NH) * 2 + ni] = __builtin_amdgcn_mfma_f32_16x16x32_f16( \
            A_[mi][1], B_[ni][1], acc[(MH) * 4 + mi][(NH) * 2 + ni], 0, 0, 0);     \
    }
#define SB0 __builtin_amdgcn_sched_barrier(0)

// ---------------- 256x256 gemm_bt core (R7-verified: 42% MfmaUtil) ----------
__device__ __forceinline__ void gemm256_core(const _Float16* A, long lda,
                                             const _Float16* B, long ldb,
                                             int K, floatx4 acc[8][4],
                                             _Float16* lds) {
    GEMM_PRELUDE
    half8 a_lo[4][2], a_hi[4][2], b_lo[2][2], b_hi[2][2];
    STAGE(0, 0);
    asm volatile("s_waitcnt vmcnt(0)" ::: "memory");
    __builtin_amdgcn_s_barrier();
    SB0;
#pragma unroll 1
    for (int t = 0; t < NT; ++t) {
        const int buf = t & 1;
        if (t + 1 < NT) { STAGE(buf ^ 1, t + 1); }
        const _Float16* Ah = lds + buf * 32768 + wr * 8192;
        const _Float16* Bh = lds + buf * 32768 + 16384 + (wc >> 1) * 8192;
        READ_A(a_lo, Ah, 0);
        READ_B(b_lo, Bh, 0);
        SB0;
        READ_A(a_hi, Ah, 1);
        SB0;
        READ_B(b_hi, Bh, 1);
        asm volatile("s_waitcnt lgkmcnt(12)" ::: "memory");
        SB0;
        MFMA_Q(0, 0, a_lo, b_lo);
        asm volatile("s_waitcnt lgkmcnt(4)" ::: "memory");
        SB0;
        MFMA_Q(1, 0, a_hi, b_lo);
        asm volatile("s_waitcnt lgkmcnt(0)" ::: "memory");
        SB0;
        MFMA_Q(0, 1, a_lo, b_hi);
        MFMA_Q(1, 1, a_hi, b_hi);
        asm volatile("s_waitcnt vmcnt(0)" ::: "memory");
        __builtin_amdgcn_s_barrier();
        SB0;
    }
}

// ---------------- pv variant: per-row fp16 A-scaling from LDS table --------
__device__ __forceinline__ void gemm256_core_pv(const _Float16* A, long lda,
                                                const _Float16* B, long ldb,
                                                int K, floatx4 acc[8][4],
                                                _Float16* lds, const float* scl) {
    GEMM_PRELUDE
    half8 a_lo[4][2], a_hi[4][2], b_lo[2][2], b_hi[2][2];
    STAGE(0, 0);
    asm volatile("s_waitcnt vmcnt(0)" ::: "memory");
    __builtin_amdgcn_s_barrier();
    SB0;
#pragma unroll 1
    for (int t = 0; t < NT; ++t) {
        const int buf = t & 1;
        if (t + 1 < NT) { STAGE(buf ^ 1, t + 1); }
        const _Float16* Ah = lds + buf * 32768 + wr * 8192;
        const _Float16* Bh = lds + buf * 32768 + 16384 + (wc >> 1) * 8192;
        const float* srow = scl + (t >> 2) * 256 + wr * 128 + rsel;
        float s_lo[4], s_hi[4];
#pragma unroll
        for (int mi = 0; mi < 4; ++mi) s_lo[mi] = srow[mi * 16];
#pragma unroll
        for (int mi = 0; mi < 4; ++mi) s_hi[mi] = srow[64 + mi * 16];
        SB0;
        READ_A(a_lo, Ah, 0);
        READ_B(b_lo, Bh, 0);
        SB0;
        READ_A(a_hi, Ah, 1);
        SB0;
        READ_B(b_hi, Bh, 1);
        asm volatile("s_waitcnt lgkmcnt(12)" ::: "memory");
        SB0;
#pragma unroll
        for (int mi = 0; mi < 4; ++mi) {
            const _Float16 h = (_Float16)s_lo[mi];
            a_lo[mi][0] = a_lo[mi][0] * h;
            a_lo[mi][1] = a_lo[mi][1] * h;
        }
        MFMA_Q(0, 0, a_lo, b_lo);
        asm volatile("s_waitcnt lgkmcnt(4)" ::: "memory");
        SB0;
#pragma unroll
        for (int mi = 0; mi < 4; ++mi) {
            const _Float16 h = (_Float16)s_hi[mi];
            a_hi[mi][0] = a_hi[mi][0] * h;
            a_hi[mi][1] = a_hi[mi][1] * h;
        }
        MFMA_Q(1, 0, a_hi, b_lo);
        asm volatile("s_waitcnt lgkmcnt(0)" ::: "memory");
        SB0;
        MFMA_Q(0, 1, a_lo, b_hi);
        MFMA_Q(1, 1, a_hi, b_hi);
        asm volatile("s_waitcnt vmcnt(0)" ::: "memory");
        __builtin_amdgcn_s_barrier();
        SB0;
    }
}

__device__ __forceinline__ void zero_acc8(floatx4 acc[8][4]) {
    const floatx4 z = {0.f, 0.f, 0.f, 0.f};
#pragma unroll
    for (int m = 0; m < 8; ++m)
#pragma unroll
        for (int n = 0; n < 4; ++n) acc[m][n] = z;
}

// ---------------- kernels ----------------

// merged prep: blocks [0,16384) build X fp16; [16384,20480) convert weights.
__global__ __launch_bounds__(256) void prep_kernel(const float* e1, const float* e2,
                                                   const float* e3, const float* Wq,
                                                   const float* Wk, const float* Wv,
                                                   const float* Wf, _Float16* X,
                                                   _Float16* Wdst) {
    const int bid = blockIdx.x;
    if (bid < 16384) {
        long i = ((long)bid * 256 + threadIdx.x) * 4;
        int m = (int)(i >> 10);
        int c = (int)(i & 1023);
        const float* src;
        if (c < 256)      src = e1 + (long)m * 256 + c;
        else if (c < 512) src = e2 + (long)m * 256 + (c - 256);
        else              src = e3 + (long)m * 512 + (c - 512);
        float4 f = *(const float4*)src;
        half4v h;
        h[0] = (_Float16)f.x; h[1] = (_Float16)f.y;
        h[2] = (_Float16)f.z; h[3] = (_Float16)f.w;
        *(half4v*)&X[i] = h;
    } else {
        long i = ((long)(bid - 16384) * 256 + threadIdx.x) * 4;
        int which = (int)(i >> 20);
        long off = i & 1048575;
        const float* w = which == 0 ? Wq : which == 1 ? Wk : which == 2 ? Wv : Wf;
        float4 f = *(const float4*)(w + off);
        half4v h;
        h[0] = (_Float16)f.x; h[1] = (_Float16)f.y;
        h[2] = (_Float16)f.z; h[3] = (_Float16)f.w;
        *(half4v*)&Wdst[i] = h;
    }
}

// QKV projection: z=0 -> q, z=1 -> k; z=2 -> vT via LDS transpose.
__global__ __launch_bounds__(512, 2) void qkv_kernel(const _Float16* X, const _Float16* W,
                                                     const float* bq, const float* bk,
                                                     const float* bv, _Float16* q,
                                                     _Float16* k, _Float16* vT) {
    extern __shared__ _Float16 lds[];
    const int m0 = blockIdx.x * 256;
    const int n0 = blockIdx.y * 256;
    const int z  = blockIdx.z;
    floatx4 acc[8][4];
    zero_acc8(acc);
    gemm256_core(X + (long)m0 * 1024, 1024,
                 W + (long)z * 1048576 + (long)n0 * 1024, 1024, 1024, acc, lds);

    const float* bias = (z == 0) ? bq : (z == 1) ? bk : bv;
    const int lane = threadIdx.x & 63;
    const int w = threadIdx.x >> 6;
    const int wr = w >> 2, wc = w & 3;
    const int rsel = lane & 15, gsel = lane >> 4;

    if (z == 2) {
        const int rb = wr * 128 + gsel * 4;
        const int cb = wc * 64 + rsel;
#pragma unroll
        for (int mI = 0; mI < 8; ++mI) {
#pragma unroll
            for (int nI = 0; nI < 4; ++nI) {
                const int c = cb + nI * 16;
                const int r = rb + mI * 16;
                const float bb = bias[n0 + c];
                half4v vv;
#pragma unroll
                for (int j = 0; j < 4; ++j) vv[j] = (_Float16)(acc[mI][nI][j] + bb);
                *(half4v*)&lds[c * 256 + (r ^ ((c & 7) << 3))] = vv;
            }
        }
        __syncthreads();
#pragma unroll
        for (int it = 0; it < 16; ++it) {
            const int idx = it * 512 + threadIdx.x;  // 0..8191
            const int c = idx >> 5;
            const int mc = idx & 31;
            half8 v = *(const half8*)&lds[c * 256 + ((mc * 8) ^ ((c & 7) << 3))];
            *(half8*)&vT[(long)(n0 + c) * 16384 + m0 + mc * 8] = v;
        }
    } else {
        _Float16* dst = (z == 0) ? q : k;
        const int r0 = m0 + wr * 128 + gsel * 4;
        const int c0 = n0 + wc * 64 + rsel;
#pragma unroll
        for (int mI = 0; mI < 8; ++mI) {
#pragma unroll
            for (int nI = 0; nI < 4; ++nI) {
                const int r = r0 + mI * 16;
                const int c = c0 + nI * 16;
                const float bb = bias[c];
#pragma unroll
                for (int j = 0; j < 4; ++j)
                    dst[(long)(r + j) * 1024 + c] = (_Float16)(acc[mI][nI][j] + bb);
            }
        }
    }
}

// scores + partial softmax: es[b,q,kv] = exp(q.k - rowtilemax) fp16 (coalesced
// via 128KB LDS transpose, double-XOR swizzle); tmax/tsum fp32 partials.
// Grid: x = batch (8, XCD-affine), y = mtile*8 + ntile.
__global__ __launch_bounds__(512, 2) void scores_kernel(const _Float16* qh,
                                                        const _Float16* kh,
                                                        _Float16* es, float* tmax,
                                                        float* tsum) {
    extern __shared__ _Float16 lds[];
    const int b = blockIdx.x;
    const int m0 = (blockIdx.y >> 3) * 256;
    const int tile = blockIdx.y & 7;
    const int n0 = tile * 256;
    floatx4 acc[8][4];
    zero_acc8(acc);
    gemm256_core(qh + ((long)b * 2048 + m0) * 1024, 1024,
                 kh + ((long)b * 2048 + n0) * 1024, 1024, 1024, acc, lds);

    const int lane = threadIdx.x & 63;
    const int w = threadIdx.x >> 6;
    const int wr = w >> 2, wc = w & 3;
    const int rsel = lane & 15, gsel = lane >> 4;
    float* red = (float*)lds;  // [256][4]

    // ---- per-(row, tile) max: over n (reg) -> rsel (shfl) -> wc (LDS)
    float mx[8][4];
#pragma unroll
    for (int m = 0; m < 8; ++m)
#pragma unroll
        for (int j = 0; j < 4; ++j) {
            float v = acc[m][0][j];
#pragma unroll
            for (int n = 1; n < 4; ++n) v = fmaxf(v, acc[m][n][j]);
#pragma unroll
            for (int d = 1; d < 16; d <<= 1) v = fmaxf(v, __shfl_xor(v, d));
            mx[m][j] = v;
        }
    if (rsel == 0) {
#pragma unroll
        for (int m = 0; m < 8; ++m)
#pragma unroll
            for (int j = 0; j < 4; ++j)
                red[(wr * 128 + m * 16 + gsel * 4 + j) * 4 + wc] = mx[m][j];
    }
    __syncthreads();
#pragma unroll
    for (int m = 0; m < 8; ++m)
#pragma unroll
        for (int j = 0; j < 4; ++j) {
            const int row = wr * 128 + m * 16 + gsel * 4 + j;
            float4 rv = *(const float4*)&red[row * 4];
            mx[m][j] = fmaxf(fmaxf(rv.x, rv.y), fmaxf(rv.z, rv.w));
        }
    __syncthreads();

    // ---- exp in place + per-(row, tile) sum
    float sm[8][4];
#pragma unroll
    for (int m = 0; m < 8; ++m)
#pragma unroll
        for (int j = 0; j < 4; ++j) {
            float s = 0.f;
#pragma unroll
            for (int n = 0; n < 4; ++n) {
                float e = __expf(acc[m][n][j] - mx[m][j]);
                acc[m][n][j] = e;
                s += e;
            }
#pragma unroll
            for (int d = 1; d < 16; d <<= 1) s += __shfl_xor(s, d);
            sm[m][j] = s;
        }
    if (rsel == 0) {
#pragma unroll
        for (int m = 0; m < 8; ++m)
#pragma unroll
            for (int j = 0; j < 4; ++j)
                red[(wr * 128 + m * 16 + gsel * 4 + j) * 4 + wc] = sm[m][j];
    }
    __syncthreads();
    if (wc == 0 && rsel == 0) {
        const long base = ((long)b * 8 + tile) * 2048 + m0;
#pragma unroll
        for (int m = 0; m < 8; ++m)
#pragma unroll
            for (int j = 0; j < 4; ++j) {
                const int row = wr * 128 + m * 16 + gsel * 4 + j;
                float4 rv = *(const float4*)&red[row * 4];
                tmax[base + row] = mx[m][j];
                tsum[base + row] = rv.x + rv.y + rv.z + rv.w;
            }
    }
    __syncthreads();  // red reads done before LDS reuse as transpose buffer

    // ---- transpose-store es via LDS [c=kv 256][r=q 256] fp16.
    // swizzle s(c) = (c&7)^((c>>3)&7) applied to r bits 3-5: conflict-free-ish
    // on both the 8B fragment writes and the strided readback.
#pragma unroll
    for (int m = 0; m < 8; ++m) {
        const int r = wr * 128 + m * 16 + gsel * 4;
#pragma unroll
        for (int n = 0; n < 4; ++n) {
            const int c = wc * 64 + n * 16 + rsel;
            const int s = (c & 7) ^ ((c >> 3) & 7);
            half4v hv;
#pragma unroll
            for (int j = 0; j < 4; ++j) hv[j] = (_Float16)acc[m][n][j];
            *(half4v*)&lds[c * 256 + (r ^ (s << 3))] = hv;
        }
    }
    __syncthreads();
    const long rbase = (long)b * 2048 * 2048;
#pragma unroll
    for (int it = 0; it < 16; ++it) {
        const int idx = it * 512 + threadIdx.x;  // 0..8191
        const int r = idx >> 5;                  // q row local
        const int chunk = idx & 31;              // kv 16B chunk
        half8 h;
#pragma unroll
        for (int e = 0; e < 8; ++e) {
            const int c = chunk * 8 + e;
            const int s = e ^ (chunk & 7);
            h[e] = lds[c * 256 + (r ^ (s << 3))];
        }
        *(half8*)&es[rbase + (long)(m0 + r) * 2048 + n0 + chunk * 8] = h;
    }
}

// cross-tile softmax reduce: scale[b][t][row] = exp(m_t - m_g) / Z
__global__ __launch_bounds__(256) void sm_reduce_kernel(const float* tmax,
                                                        const float* tsum,
                                                        float* scale) {
    const int idx = blockIdx.x * 256 + threadIdx.x;  // < 8*2048
    const int b = idx >> 11, row = idx & 2047;
    const float* mrow = tmax + (long)b * 8 * 2048 + row;
    const float* srow = tsum + (long)b * 8 * 2048 + row;
    float m[8];
    float mg = -1e30f;
#pragma unroll
    for (int t = 0; t < 8; ++t) {
        m[t] = mrow[(long)t * 2048];
        mg = fmaxf(mg, m[t]);
    }
    float Z = 0.f;
#pragma unroll
    for (int t = 0; t < 8; ++t) Z += srow[(long)t * 2048] * __expf(m[t] - mg);
    const float inv = 1.0f / Z;
    float* orow = scale + (long)b * 8 * 2048 + row;
#pragma unroll
    for (int t = 0; t < 8; ++t) orow[(long)t * 2048] = __expf(m[t] - mg) * inv;
}

// weighted[b] = (es * scale)[b] @ v[b] via vT. fp16 out [16384][1024].
// Grid: x = batch (8, XCD-affine), y = mtile*4 + ntile.
__global__ __launch_bounds__(512, 2) void pv_kernel(const _Float16* es,
                                                    const _Float16* vT,
                                                    const float* scale_g,
                                                    _Float16* wt) {
    extern __shared__ _Float16 lds[];
    const int batch = blockIdx.x;
    const int m0 = (blockIdx.y >> 2) * 256;
    const int n0 = (blockIdx.y & 3) * 256;
    float* scl = (float*)(lds + 65536);
    for (int i = threadIdx.x; i < 2048; i += 512) {
        const int t8 = i >> 8, rl = i & 255;
        scl[i] = scale_g[((long)batch * 8 + t8) * 2048 + m0 + rl];
    }
    __syncthreads();
    floatx4 acc[8][4];
    zero_acc8(acc);
    gemm256_core_pv(es + ((long)batch * 2048 + m0) * 2048, 2048,
                    vT + (long)n0 * 16384 + (long)batch * 2048, 16384, 2048, acc,
                    lds, scl);

    const int lane = threadIdx.x & 63;
    const int w = threadIdx.x >> 6;
    const int wr = w >> 2, wc = w & 3;
    const int r0 = wr * 128 + (lane >> 4) * 4;
    const int c0 = n0 + wc * 64 + (lane & 15);
#pragma unroll
    for (int m = 0; m < 8; ++m) {
#pragma unroll
        for (int n = 0; n < 4; ++n) {
            const int r = r0 + m * 16;
            const int c = c0 + n * 16;
#pragma unroll
            for (int j = 0; j < 4; ++j)
                wt[((long)batch * 2048 + m0 + r + j) * 1024 + c] =
                    (_Float16)acc[m][n][j];
        }
    }
}

// out = leakyrelu(weighted @ Wf^T + bf), fp32 out.
__global__ __launch_bounds__(512, 2) void out_kernel(const _Float16* wt, const _Float16* Wf,
                                                     const float* bf_, float* out) {
    extern __shared__ _Float16 lds[];
    const int m0 = blockIdx.x * 256;
    const int n0 = blockIdx.y * 256;
    floatx4 acc[8][4];
    zero_acc8(acc);
    gemm256_core(wt + (long)m0 * 1024, 1024, Wf + (long)n0 * 1024, 1024, 1024, acc, lds);

    const int lane = threadIdx.x & 63;
    const int w = threadIdx.x >> 6;
    const int wr = w >> 2, wc = w & 3;
    const int r0 = m0 + wr * 128 + (lane >> 4) * 4;
    const int c0 = n0 + wc * 64 + (lane & 15);
#pragma unroll
    for (int m = 0; m < 8; ++m) {
#pragma unroll
        for (int n = 0; n < 4; ++n) {
            const int r = r0 + m * 16;
            const int c = c0 + n * 16;
            const float bb = bf_[c];
#pragma unroll
            for (int j = 0; j < 4; ++j) {
                float y = acc[m][n][j] + bb;
                y = (y >= 0.f) ? y : 0.2f * y;
                out[(long)(r + j) * 1024 + c] = y;
            }
        }
    }
}

// ---------------- launcher ----------------
extern "C" void kernel_launch(void* const* d_in, const int* in_sizes, int n_in,
                              void* d_out, int out_size, void* d_ws, size_t ws_size,
                              hipStream_t stream) {
    const float* e1 = (const float*)d_in[0];
    const float* e2 = (const float*)d_in[1];
    const float* e3 = (const float*)d_in[2];
    const float* Wq = (const float*)d_in[3];
    const float* bq = (const float*)d_in[4];
    const float* Wk = (const float*)d_in[5];
    const float* bk = (const float*)d_in[6];
    const float* Wv = (const float*)d_in[7];
    const float* bv = (const float*)d_in[8];
    const float* Wf = (const float*)d_in[9];
    const float* bf_ = (const float*)d_in[10];
    float* out = (float*)d_out;

    const int LDS_BYTES = 131072;
    const int LDS_PV = 131072 + 8192;
    (void)hipFuncSetAttribute((const void*)qkv_kernel,
                              hipFuncAttributeMaxDynamicSharedMemorySize, LDS_BYTES);
    (void)hipFuncSetAttribute((const void*)scores_kernel,
                              hipFuncAttributeMaxDynamicSharedMemorySize, LDS_BYTES);
    (void)hipFuncSetAttribute((const void*)pv_kernel,
                              hipFuncAttributeMaxDynamicSharedMemorySize, LDS_PV);
    (void)hipFuncSetAttribute((const void*)out_kernel,
                              hipFuncAttributeMaxDynamicSharedMemorySize, LDS_BYTES);

    char* ws = (char*)d_ws;
    const size_t MB = 1024 * 1024;
    _Float16* Xh    = (_Float16*)(ws + 0);        // 32 MiB
    _Float16* Wh    = (_Float16*)(ws + 32 * MB);  // 8 MiB
    _Float16* qh    = (_Float16*)(ws + 40 * MB);  // 32 MiB
    _Float16* kh    = (_Float16*)(ws + 72 * MB);  // 32 MiB
    _Float16* vT    = (_Float16*)(ws + 104 * MB); // 32 MiB [1024][16384]
    _Float16* wt    = (_Float16*)(ws + 136 * MB); // 32 MiB
    _Float16* es    = (_Float16*)(ws + 168 * MB); // 64 MiB [8][2048][2048] fp16
    float* tmax     = (float*)(ws + 232 * MB);              // 512 KiB [8][8][2048]
    float* tsum     = (float*)(ws + 232 * MB + 524288);     // 512 KiB
    float* scale    = (float*)(ws + 233 * MB);              // 512 KiB

    prep_kernel<<<20480, 256, 0, stream>>>(e1, e2, e3, Wq, Wk, Wv, Wf, Xh, Wh);
    qkv_kernel<<<dim3(64, 4, 3), 512, LDS_BYTES, stream>>>(Xh, Wh, bq, bk, bv, qh, kh, vT);
    scores_kernel<<<dim3(8, 64), 512, LDS_BYTES, stream>>>(qh, kh, es, tmax, tsum);
    sm_reduce_kernel<<<64, 256, 0, stream>>>(tmax, tsum, scale);
    pv_kernel<<<dim3(8, 32), 512, LDS_PV, stream>>>(es, vT, scale, wt);
    out_kernel<<<dim3(64, 4), 512, LDS_BYTES, stream>>>(wt, Wh + 3 * 1048576, bf_, out);
}

// Round 11
// 313.209 us; speedup vs baseline: 1.7159x; 1.1614x over previous
//
#include <hip/hip_runtime.h>
#include <hip/hip_fp16.h>

typedef _Float16 half8 __attribute__((ext_vector_type(8)));
typedef _Float16 half4v __attribute__((ext_vector_type(4)));
typedef float floatx4 __attribute__((ext_vector_type(4)));

// ---------------- async global->LDS (16B per lane) ----------------
__device__ __forceinline__ void load_lds16(const void* g, void* l) {
    __builtin_amdgcn_global_load_lds(
        (const __attribute__((address_space(1))) void*)g,
        (__attribute__((address_space(3))) void*)l,
        16, 0, 0);
}

// Stage one 128x64 fp16 half-tile (16 KiB) into LDS. LDS dest linear;
// SOURCE slot XOR-pre-swizzled (slot ^= row&7) -- Guideline 21.
__device__ __forceinline__ void stage_half(const _Float16* g, long ld, _Float16* dst) {
    const int t = threadIdx.x;  // 512 threads x 2 chunks x 16B
#pragma unroll
    for (int j = 0; j < 2; ++j) {
        const int c = j * 512 + t;             // 0..1023
        const int row = c >> 3;                // 0..127
        const int slot = (c & 7) ^ (row & 7);  // pre-swizzled source slot
        load_lds16(g + (long)row * ld + slot * 8, dst + c * 8);
    }
}

#define GEMM_PRELUDE                                                               \
    const int lane = threadIdx.x & 63;                                             \
    const int w    = threadIdx.x >> 6;                                             \
    const int wr   = w >> 2;                                                       \
    const int wc   = w & 3;                                                        \
    const int rsel = lane & 15, gsel = lane >> 4;                                  \
    const int NT = K >> 6;                                                         \
    (void)lane;
#define STAGE(BUF, KT)                                                             \
    stage_half(A + (KT) * 64, lda, lds + (BUF) * 32768);                           \
    stage_half(A + (long)128 * lda + (KT) * 64, lda, lds + (BUF) * 32768 + 8192);  \
    stage_half(B + (KT) * 64, ldb, lds + (BUF) * 32768 + 16384);                   \
    stage_half(B + (long)128 * ldb + (KT) * 64, ldb, lds + (BUF) * 32768 + 24576);
#define READ_A(dst, AH, MH)                                                        \
    _Pragma("unroll") for (int mi = 0; mi < 4; ++mi) {                             \
        const int r = ((MH) * 4 + mi) * 16 + rsel;                                 \
        dst[mi][0] = *(const half8*)&(AH)[r * 64 + ((gsel ^ (r & 7)) << 3)];       \
        dst[mi][1] = *(const half8*)&(AH)[r * 64 + (((4 + gsel) ^ (r & 7)) << 3)]; \
    }
#define READ_B(dst, BH, NH)                                                        \
    _Pragma("unroll") for (int ni = 0; ni < 2; ++ni) {                             \
        const int rn = (wc & 1) * 64 + ((NH) * 2 + ni) * 16 + rsel;                \
        dst[ni][0] = *(const half8*)&(BH)[rn * 64 + ((gsel ^ (rn & 7)) << 3)];     \
        dst[ni][1] = *(const half8*)&(BH)[rn * 64 + (((4 + gsel) ^ (rn & 7)) << 3)]; \
    }
#define MFMA_Q(MH, NH, A_, B_)                                                     \
    _Pragma("unroll") for (int mi = 0; mi < 4; ++mi)                               \
    _Pragma("unroll") for (int ni = 0; ni < 2; ++ni) {                             \
        acc[(MH) * 4 + mi][(NH) * 2 + ni] = __builtin_amdgcn_mfma_f32_16x16x32_f16( \
            A_[mi][0], B_[ni][0], acc[(MH) * 4 + mi][(NH) * 2 + ni], 0, 0, 0);     \
        acc[(MH) * 4 + mi][(NH) * 2 + ni] = __builtin_amdgcn_mfma_f32_16x16x32_f16( \
            A_[mi][1], B_[ni][1], acc[(MH) * 4 + mi][(NH) * 2 + ni], 0, 0, 0);     \
    }
#define SB0 __builtin_amdgcn_sched_barrier(0)

// ---------------- 256x256 gemm_bt core (R7-verified) ----------
__device__ __forceinline__ void gemm256_core(const _Float16* A, long lda,
                                             const _Float16* B, long ldb,
                                             int K, floatx4 acc[8][4],
                                             _Float16* lds) {
    GEMM_PRELUDE
    half8 a_lo[4][2], a_hi[4][2], b_lo[2][2], b_hi[2][2];
    STAGE(0, 0);
    asm volatile("s_waitcnt vmcnt(0)" ::: "memory");
    __builtin_amdgcn_s_barrier();
    SB0;
#pragma unroll 1
    for (int t = 0; t < NT; ++t) {
        const int buf = t & 1;
        if (t + 1 < NT) { STAGE(buf ^ 1, t + 1); }
        const _Float16* Ah = lds + buf * 32768 + wr * 8192;
        const _Float16* Bh = lds + buf * 32768 + 16384 + (wc >> 1) * 8192;
        READ_A(a_lo, Ah, 0);
        READ_B(b_lo, Bh, 0);
        SB0;
        READ_A(a_hi, Ah, 1);
        SB0;
        READ_B(b_hi, Bh, 1);
        asm volatile("s_waitcnt lgkmcnt(12)" ::: "memory");
        SB0;
        MFMA_Q(0, 0, a_lo, b_lo);
        asm volatile("s_waitcnt lgkmcnt(4)" ::: "memory");
        SB0;
        MFMA_Q(1, 0, a_hi, b_lo);
        asm volatile("s_waitcnt lgkmcnt(0)" ::: "memory");
        SB0;
        MFMA_Q(0, 1, a_lo, b_hi);
        MFMA_Q(1, 1, a_hi, b_hi);
        asm volatile("s_waitcnt vmcnt(0)" ::: "memory");
        __builtin_amdgcn_s_barrier();
        SB0;
    }
}

// ---------------- pv variant: per-row fp16 A-scaling from LDS table --------
__device__ __forceinline__ void gemm256_core_pv(const _Float16* A, long lda,
                                                const _Float16* B, long ldb,
                                                int K, floatx4 acc[8][4],
                                                _Float16* lds, const float* scl) {
    GEMM_PRELUDE
    half8 a_lo[4][2], a_hi[4][2], b_lo[2][2], b_hi[2][2];
    STAGE(0, 0);
    asm volatile("s_waitcnt vmcnt(0)" ::: "memory");
    __builtin_amdgcn_s_barrier();
    SB0;
#pragma unroll 1
    for (int t = 0; t < NT; ++t) {
        const int buf = t & 1;
        if (t + 1 < NT) { STAGE(buf ^ 1, t + 1); }
        const _Float16* Ah = lds + buf * 32768 + wr * 8192;
        const _Float16* Bh = lds + buf * 32768 + 16384 + (wc >> 1) * 8192;
        const float* srow = scl + (t >> 2) * 256 + wr * 128 + rsel;
        float s_lo[4], s_hi[4];
#pragma unroll
        for (int mi = 0; mi < 4; ++mi) s_lo[mi] = srow[mi * 16];
#pragma unroll
        for (int mi = 0; mi < 4; ++mi) s_hi[mi] = srow[64 + mi * 16];
        SB0;
        READ_A(a_lo, Ah, 0);
        READ_B(b_lo, Bh, 0);
        SB0;
        READ_A(a_hi, Ah, 1);
        SB0;
        READ_B(b_hi, Bh, 1);
        asm volatile("s_waitcnt lgkmcnt(12)" ::: "memory");
        SB0;
#pragma unroll
        for (int mi = 0; mi < 4; ++mi) {
            const _Float16 h = (_Float16)s_lo[mi];
            a_lo[mi][0] = a_lo[mi][0] * h;
            a_lo[mi][1] = a_lo[mi][1] * h;
        }
        MFMA_Q(0, 0, a_lo, b_lo);
        asm volatile("s_waitcnt lgkmcnt(4)" ::: "memory");
        SB0;
#pragma unroll
        for (int mi = 0; mi < 4; ++mi) {
            const _Float16 h = (_Float16)s_hi[mi];
            a_hi[mi][0] = a_hi[mi][0] * h;
            a_hi[mi][1] = a_hi[mi][1] * h;
        }
        MFMA_Q(1, 0, a_hi, b_lo);
        asm volatile("s_waitcnt lgkmcnt(0)" ::: "memory");
        SB0;
        MFMA_Q(0, 1, a_lo, b_hi);
        MFMA_Q(1, 1, a_hi, b_hi);
        asm volatile("s_waitcnt vmcnt(0)" ::: "memory");
        __builtin_amdgcn_s_barrier();
        SB0;
    }
}

__device__ __forceinline__ void zero_acc8(floatx4 acc[8][4]) {
    const floatx4 z = {0.f, 0.f, 0.f, 0.f};
#pragma unroll
    for (int m = 0; m < 8; ++m)
#pragma unroll
        for (int n = 0; n < 4; ++n) acc[m][n] = z;
}

// ---------------- kernels ----------------

// merged prep: blocks [0,16384) build X fp16; [16384,20480) convert weights.
__global__ __launch_bounds__(256) void prep_kernel(const float* e1, const float* e2,
                                                   const float* e3, const float* Wq,
                                                   const float* Wk, const float* Wv,
                                                   const float* Wf, _Float16* X,
                                                   _Float16* Wdst) {
    const int bid = blockIdx.x;
    if (bid < 16384) {
        long i = ((long)bid * 256 + threadIdx.x) * 4;
        int m = (int)(i >> 10);
        int c = (int)(i & 1023);
        const float* src;
        if (c < 256)      src = e1 + (long)m * 256 + c;
        else if (c < 512) src = e2 + (long)m * 256 + (c - 256);
        else              src = e3 + (long)m * 512 + (c - 512);
        float4 f = *(const float4*)src;
        half4v h;
        h[0] = (_Float16)f.x; h[1] = (_Float16)f.y;
        h[2] = (_Float16)f.z; h[3] = (_Float16)f.w;
        *(half4v*)&X[i] = h;
    } else {
        long i = ((long)(bid - 16384) * 256 + threadIdx.x) * 4;
        int which = (int)(i >> 20);
        long off = i & 1048575;
        const float* w = which == 0 ? Wq : which == 1 ? Wk : which == 2 ? Wv : Wf;
        float4 f = *(const float4*)(w + off);
        half4v h;
        h[0] = (_Float16)f.x; h[1] = (_Float16)f.y;
        h[2] = (_Float16)f.z; h[3] = (_Float16)f.w;
        *(half4v*)&Wdst[i] = h;
    }
}

// QKV projection: z=0 -> q, z=1 -> k; z=2 -> vT via LDS transpose.
__global__ __launch_bounds__(512, 2) void qkv_kernel(const _Float16* X, const _Float16* W,
                                                     const float* bq, const float* bk,
                                                     const float* bv, _Float16* q,
                                                     _Float16* k, _Float16* vT) {
    extern __shared__ _Float16 lds[];
    const int m0 = blockIdx.x * 256;
    const int n0 = blockIdx.y * 256;
    const int z  = blockIdx.z;
    floatx4 acc[8][4];
    zero_acc8(acc);
    gemm256_core(X + (long)m0 * 1024, 1024,
                 W + (long)z * 1048576 + (long)n0 * 1024, 1024, 1024, acc, lds);

    const float* bias = (z == 0) ? bq : (z == 1) ? bk : bv;
    const int lane = threadIdx.x & 63;
    const int w = threadIdx.x >> 6;
    const int wr = w >> 2, wc = w & 3;
    const int rsel = lane & 15, gsel = lane >> 4;

    if (z == 2) {
        const int rb = wr * 128 + gsel * 4;
        const int cb = wc * 64 + rsel;
#pragma unroll
        for (int mI = 0; mI < 8; ++mI) {
#pragma unroll
            for (int nI = 0; nI < 4; ++nI) {
                const int c = cb + nI * 16;
                const int r = rb + mI * 16;
                const float bb = bias[n0 + c];
                half4v vv;
#pragma unroll
                for (int j = 0; j < 4; ++j) vv[j] = (_Float16)(acc[mI][nI][j] + bb);
                *(half4v*)&lds[c * 256 + (r ^ ((c & 7) << 3))] = vv;
            }
        }
        __syncthreads();
#pragma unroll
        for (int it = 0; it < 16; ++it) {
            const int idx = it * 512 + threadIdx.x;  // 0..8191
            const int c = idx >> 5;
            const int mc = idx & 31;
            half8 v = *(const half8*)&lds[c * 256 + ((mc * 8) ^ ((c & 7) << 3))];
            *(half8*)&vT[(long)(n0 + c) * 16384 + m0 + mc * 8] = v;
        }
    } else {
        _Float16* dst = (z == 0) ? q : k;
        const int r0 = m0 + wr * 128 + gsel * 4;
        const int c0 = n0 + wc * 64 + rsel;
#pragma unroll
        for (int mI = 0; mI < 8; ++mI) {
#pragma unroll
            for (int nI = 0; nI < 4; ++nI) {
                const int r = r0 + mI * 16;
                const int c = c0 + nI * 16;
                const float bb = bias[c];
#pragma unroll
                for (int j = 0; j < 4; ++j)
                    dst[(long)(r + j) * 1024 + c] = (_Float16)(acc[mI][nI][j] + bb);
            }
        }
    }
}

// scores + partial softmax, SPILL-FREE epilogue (VGPR cap is 128 with 128
// AGPR acc at 8 waves/CU; the old mx[32]+sm[32] live arrays spilled to
// scratch -> ~124MB of HBM write traffic + latency stalls).
// P1 partial-max -> red; P2 finalize+exp+partial-sum -> red2 (values read
// from LDS at use time, never held); P3 fold partials -> tmax/tsum;
// P4 transpose-write; P5 coalesced es store.
__global__ __launch_bounds__(512, 2) void scores_kernel(const _Float16* qh,
                                                        const _Float16* kh,
                                                        _Float16* es, float* tmax,
                                                        float* tsum) {
    extern __shared__ _Float16 lds[];
    const int b = blockIdx.x;
    const int m0 = (blockIdx.y >> 3) * 256;
    const int tile = blockIdx.y & 7;
    const int n0 = tile * 256;
    floatx4 acc[8][4];
    zero_acc8(acc);
    gemm256_core(qh + ((long)b * 2048 + m0) * 1024, 1024,
                 kh + ((long)b * 2048 + n0) * 1024, 1024, 1024, acc, lds);

    const int lane = threadIdx.x & 63;
    const int w = threadIdx.x >> 6;
    const int wr = w >> 2, wc = w & 3;
    const int rsel = lane & 15, gsel = lane >> 4;
    float* red  = (float*)lds;         // [256][4] partial max
    float* red2 = (float*)lds + 1024;  // [256][4] partial sum

    // ---- P1: partial max over n (reg) + rsel (shfl) -> red[row][wc]
#pragma unroll
    for (int m = 0; m < 8; ++m) {
#pragma unroll
        for (int j = 0; j < 4; ++j) {
            float v = acc[m][0][j];
#pragma unroll
            for (int n = 1; n < 4; ++n) v = fmaxf(v, acc[m][n][j]);
#pragma unroll
            for (int d = 1; d < 16; d <<= 1) v = fmaxf(v, __shfl_xor(v, d));
            if (rsel == 0) red[(wr * 128 + m * 16 + gsel * 4 + j) * 4 + wc] = v;
        }
    }
    __syncthreads();

    // ---- P2: read partials at use time, finalize max, exp, partial sum
#pragma unroll
    for (int m = 0; m < 8; ++m) {
#pragma unroll
        for (int j = 0; j < 4; ++j) {
            const int row = wr * 128 + m * 16 + gsel * 4 + j;
            float4 rv = *(const float4*)&red[row * 4];
            const float mxv = fmaxf(fmaxf(rv.x, rv.y), fmaxf(rv.z, rv.w));
            float s = 0.f;
#pragma unroll
            for (int n = 0; n < 4; ++n) {
                float e = __expf(acc[m][n][j] - mxv);
                acc[m][n][j] = e;
                s += e;
            }
#pragma unroll
            for (int d = 1; d < 16; d <<= 1) s += __shfl_xor(s, d);
            if (rsel == 0) red2[row * 4 + wc] = s;
        }
    }
    __syncthreads();

    // ---- P3: fold partials -> global tmax/tsum (2 lanes per wave)
    if (wc == 0 && rsel == 0) {
        const long base = ((long)b * 8 + tile) * 2048 + m0;
#pragma unroll
        for (int m = 0; m < 8; ++m) {
#pragma unroll
            for (int j = 0; j < 4; ++j) {
                const int row = wr * 128 + m * 16 + gsel * 4 + j;
                float4 rv = *(const float4*)&red[row * 4];
                float4 sv = *(const float4*)&red2[row * 4];
                tmax[base + row] = fmaxf(fmaxf(rv.x, rv.y), fmaxf(rv.z, rv.w));
                tsum[base + row] = sv.x + sv.y + sv.z + sv.w;
            }
        }
    }
    __syncthreads();  // red/red2 reads done before transpose clobbers LDS

    // ---- P4: transpose write LDS [c=kv 256][r=q 256] fp16, double-XOR swz
#pragma unroll
    for (int m = 0; m < 8; ++m) {
        const int r = wr * 128 + m * 16 + gsel * 4;
#pragma unroll
        for (int n = 0; n < 4; ++n) {
            const int c = wc * 64 + n * 16 + rsel;
            const int s = (c & 7) ^ ((c >> 3) & 7);
            half4v hv;
#pragma unroll
            for (int j = 0; j < 4; ++j) hv[j] = (_Float16)acc[m][n][j];
            *(half4v*)&lds[c * 256 + (r ^ (s << 3))] = hv;
        }
    }
    __syncthreads();
    // ---- P5: coalesced es store (512B runs per row)
    const long rbase = (long)b * 2048 * 2048;
#pragma unroll
    for (int it = 0; it < 16; ++it) {
        const int idx = it * 512 + threadIdx.x;  // 0..8191
        const int r = idx >> 5;                  // q row local
        const int chunk = idx & 31;              // kv 16B chunk
        half8 h;
#pragma unroll
        for (int e = 0; e < 8; ++e) {
            const int c = chunk * 8 + e;
            const int s = e ^ (chunk & 7);
            h[e] = lds[c * 256 + (r ^ (s << 3))];
        }
        *(half8*)&es[rbase + (long)(m0 + r) * 2048 + n0 + chunk * 8] = h;
    }
}

// weighted[b] = (es * scale)[b] @ v[b] via vT; scale computed in prologue
// from tmax/tsum (sm_reduce fused). fp16 out [16384][1024].
__global__ __launch_bounds__(512, 2) void pv_kernel(const _Float16* es,
                                                    const _Float16* vT,
                                                    const float* tmax,
                                                    const float* tsum,
                                                    _Float16* wt) {
    extern __shared__ _Float16 lds[];
    const int batch = blockIdx.x;
    const int m0 = (blockIdx.y >> 2) * 256;
    const int n0 = (blockIdx.y & 3) * 256;
    float* scl = (float*)(lds + 65536);  // [8][256] after the 128KB dbuf
    if (threadIdx.x < 256) {
        const int row = m0 + threadIdx.x;
        float m[8];
        float mg = -1e30f;
#pragma unroll
        for (int t = 0; t < 8; ++t) {
            m[t] = tmax[((long)batch * 8 + t) * 2048 + row];
            mg = fmaxf(mg, m[t]);
        }
        float Z = 0.f;
#pragma unroll
        for (int t = 0; t < 8; ++t)
            Z += tsum[((long)batch * 8 + t) * 2048 + row] * __expf(m[t] - mg);
        const float inv = 1.0f / Z;
#pragma unroll
        for (int t = 0; t < 8; ++t)
            scl[t * 256 + threadIdx.x] = __expf(m[t] - mg) * inv;
    }
    __syncthreads();
    floatx4 acc[8][4];
    zero_acc8(acc);
    gemm256_core_pv(es + ((long)batch * 2048 + m0) * 2048, 2048,
                    vT + (long)n0 * 16384 + (long)batch * 2048, 16384, 2048, acc,
                    lds, scl);

    const int lane = threadIdx.x & 63;
    const int w = threadIdx.x >> 6;
    const int wr = w >> 2, wc = w & 3;
    const int r0 = wr * 128 + (lane >> 4) * 4;
    const int c0 = n0 + wc * 64 + (lane & 15);
#pragma unroll
    for (int m = 0; m < 8; ++m) {
#pragma unroll
        for (int n = 0; n < 4; ++n) {
            const int r = r0 + m * 16;
            const int c = c0 + n * 16;
#pragma unroll
            for (int j = 0; j < 4; ++j)
                wt[((long)batch * 2048 + m0 + r + j) * 1024 + c] =
                    (_Float16)acc[m][n][j];
        }
    }
}

// out = leakyrelu(weighted @ Wf^T + bf), fp32 out.
__global__ __launch_bounds__(512, 2) void out_kernel(const _Float16* wt, const _Float16* Wf,
                                                     const float* bf_, float* out) {
    extern __shared__ _Float16 lds[];
    const int m0 = blockIdx.x * 256;
    const int n0 = blockIdx.y * 256;
    floatx4 acc[8][4];
    zero_acc8(acc);
    gemm256_core(wt + (long)m0 * 1024, 1024, Wf + (long)n0 * 1024, 1024, 1024, acc, lds);

    const int lane = threadIdx.x & 63;
    const int w = threadIdx.x >> 6;
    const int wr = w >> 2, wc = w & 3;
    const int r0 = m0 + wr * 128 + (lane >> 4) * 4;
    const int c0 = n0 + wc * 64 + (lane & 15);
#pragma unroll
    for (int m = 0; m < 8; ++m) {
#pragma unroll
        for (int n = 0; n < 4; ++n) {
            const int r = r0 + m * 16;
            const int c = c0 + n * 16;
            const float bb = bf_[c];
#pragma unroll
            for (int j = 0; j < 4; ++j) {
                float y = acc[m][n][j] + bb;
                y = (y >= 0.f) ? y : 0.2f * y;
                out[(long)(r + j) * 1024 + c] = y;
            }
        }
    }
}

// ---------------- launcher ----------------
extern "C" void kernel_launch(void* const* d_in, const int* in_sizes, int n_in,
                              void* d_out, int out_size, void* d_ws, size_t ws_size,
                              hipStream_t stream) {
    const float* e1 = (const float*)d_in[0];
    const float* e2 = (const float*)d_in[1];
    const float* e3 = (const float*)d_in[2];
    const float* Wq = (const float*)d_in[3];
    const float* bq = (const float*)d_in[4];
    const float* Wk = (const float*)d_in[5];
    const float* bk = (const float*)d_in[6];
    const float* Wv = (const float*)d_in[7];
    const float* bv = (const float*)d_in[8];
    const float* Wf = (const float*)d_in[9];
    const float* bf_ = (const float*)d_in[10];
    float* out = (float*)d_out;

    const int LDS_BYTES = 131072;
    const int LDS_PV = 131072 + 8192;
    (void)hipFuncSetAttribute((const void*)qkv_kernel,
                              hipFuncAttributeMaxDynamicSharedMemorySize, LDS_BYTES);
    (void)hipFuncSetAttribute((const void*)scores_kernel,
                              hipFuncAttributeMaxDynamicSharedMemorySize, LDS_BYTES);
    (void)hipFuncSetAttribute((const void*)pv_kernel,
                              hipFuncAttributeMaxDynamicSharedMemorySize, LDS_PV);
    (void)hipFuncSetAttribute((const void*)out_kernel,
                              hipFuncAttributeMaxDynamicSharedMemorySize, LDS_BYTES);

    char* ws = (char*)d_ws;
    const size_t MB = 1024 * 1024;
    _Float16* Xh    = (_Float16*)(ws + 0);        // 32 MiB
    _Float16* Wh    = (_Float16*)(ws + 32 * MB);  // 8 MiB
    _Float16* qh    = (_Float16*)(ws + 40 * MB);  // 32 MiB
    _Float16* kh    = (_Float16*)(ws + 72 * MB);  // 32 MiB
    _Float16* vT    = (_Float16*)(ws + 104 * MB); // 32 MiB [1024][16384]
    _Float16* wt    = (_Float16*)(ws + 136 * MB); // 32 MiB
    _Float16* es    = (_Float16*)(ws + 168 * MB); // 64 MiB [8][2048][2048] fp16
    float* tmax     = (float*)(ws + 232 * MB);              // 512 KiB [8][8][2048]
    float* tsum     = (float*)(ws + 232 * MB + 524288);     // 512 KiB

    prep_kernel<<<20480, 256, 0, stream>>>(e1, e2, e3, Wq, Wk, Wv, Wf, Xh, Wh);
    qkv_kernel<<<dim3(64, 4, 3), 512, LDS_BYTES, stream>>>(Xh, Wh, bq, bk, bv, qh, kh, vT);
    scores_kernel<<<dim3(8, 64), 512, LDS_BYTES, stream>>>(qh, kh, es, tmax, tsum);
    pv_kernel<<<dim3(8, 32), 512, LDS_PV, stream>>>(es, vT, tmax, tsum, wt);
    out_kernel<<<dim3(64, 4), 512, LDS_BYTES, stream>>>(wt, Wh + 3 * 1048576, bf_, out);
}

// Round 12
// 296.608 us; speedup vs baseline: 1.8120x; 1.0560x over previous
//
#include <hip/hip_runtime.h>
#include <hip/hip_fp16.h>

typedef _Float16 half8 __attribute__((ext_vector_type(8)));
typedef _Float16 half4v __attribute__((ext_vector_type(4)));
typedef float floatx4 __attribute__((ext_vector_type(4)));

// ---------------- async global->LDS (16B per lane) ----------------
__device__ __forceinline__ void load_lds16(const void* g, void* l) {
    __builtin_amdgcn_global_load_lds(
        (const __attribute__((address_space(1))) void*)g,
        (__attribute__((address_space(3))) void*)l,
        16, 0, 0);
}

// Stage one 128x64 fp16 half-tile (16 KiB) into LDS. LDS dest linear;
// SOURCE slot XOR-pre-swizzled (slot ^= row&7) -- Guideline 21.
__device__ __forceinline__ void stage_half(const _Float16* g, long ld, _Float16* dst) {
    const int t = threadIdx.x;  // 512 threads x 2 chunks x 16B
#pragma unroll
    for (int j = 0; j < 2; ++j) {
        const int c = j * 512 + t;             // 0..1023
        const int row = c >> 3;                // 0..127
        const int slot = (c & 7) ^ (row & 7);  // pre-swizzled source slot
        load_lds16(g + (long)row * ld + slot * 8, dst + c * 8);
    }
}

#define GEMM_PRELUDE                                                               \
    const int lane = threadIdx.x & 63;                                             \
    const int w    = threadIdx.x >> 6;                                             \
    const int wr   = w >> 2;                                                       \
    const int wc   = w & 3;                                                        \
    const int rsel = lane & 15, gsel = lane >> 4;                                  \
    const int NT = K >> 6;                                                         \
    (void)lane;
#define STAGE(BUF, KT)                                                             \
    stage_half(A + (KT) * 64, lda, lds + (BUF) * 32768);                           \
    stage_half(A + (long)128 * lda + (KT) * 64, lda, lds + (BUF) * 32768 + 8192);  \
    stage_half(B + (KT) * 64, ldb, lds + (BUF) * 32768 + 16384);                   \
    stage_half(B + (long)128 * ldb + (KT) * 64, ldb, lds + (BUF) * 32768 + 24576);
#define READ_A(dst, AH, MH)                                                        \
    _Pragma("unroll") for (int mi = 0; mi < 4; ++mi) {                             \
        const int r = ((MH) * 4 + mi) * 16 + rsel;                                 \
        dst[mi][0] = *(const half8*)&(AH)[r * 64 + ((gsel ^ (r & 7)) << 3)];       \
        dst[mi][1] = *(const half8*)&(AH)[r * 64 + (((4 + gsel) ^ (r & 7)) << 3)]; \
    }
#define READ_B(dst, BH, NH)                                                        \
    _Pragma("unroll") for (int ni = 0; ni < 2; ++ni) {                             \
        const int rn = (wc & 1) * 64 + ((NH) * 2 + ni) * 16 + rsel;                \
        dst[ni][0] = *(const half8*)&(BH)[rn * 64 + ((gsel ^ (rn & 7)) << 3)];     \
        dst[ni][1] = *(const half8*)&(BH)[rn * 64 + (((4 + gsel) ^ (rn & 7)) << 3)]; \
    }
#define MFMA_Q(MH, NH, A_, B_)                                                     \
    _Pragma("unroll") for (int mi = 0; mi < 4; ++mi)                               \
    _Pragma("unroll") for (int ni = 0; ni < 2; ++ni) {                             \
        acc[(MH) * 4 + mi][(NH) * 2 + ni] = __builtin_amdgcn_mfma_f32_16x16x32_f16( \
            A_[mi][0], B_[ni][0], acc[(MH) * 4 + mi][(NH) * 2 + ni], 0, 0, 0);     \
        acc[(MH) * 4 + mi][(NH) * 2 + ni] = __builtin_amdgcn_mfma_f32_16x16x32_f16( \
            A_[mi][1], B_[ni][1], acc[(MH) * 4 + mi][(NH) * 2 + ni], 0, 0, 0);     \
    }
#define SB0 __builtin_amdgcn_sched_barrier(0)

// ---------------- 256x256 gemm_bt core (R7-verified) ----------
__device__ __forceinline__ void gemm256_core(const _Float16* A, long lda,
                                             const _Float16* B, long ldb,
                                             int K, floatx4 acc[8][4],
                                             _Float16* lds) {
    GEMM_PRELUDE
    half8 a_lo[4][2], a_hi[4][2], b_lo[2][2], b_hi[2][2];
    STAGE(0, 0);
    asm volatile("s_waitcnt vmcnt(0)" ::: "memory");
    __builtin_amdgcn_s_barrier();
    SB0;
#pragma unroll 1
    for (int t = 0; t < NT; ++t) {
        const int buf = t & 1;
        if (t + 1 < NT) { STAGE(buf ^ 1, t + 1); }
        const _Float16* Ah = lds + buf * 32768 + wr * 8192;
        const _Float16* Bh = lds + buf * 32768 + 16384 + (wc >> 1) * 8192;
        READ_A(a_lo, Ah, 0);
        READ_B(b_lo, Bh, 0);
        SB0;
        READ_A(a_hi, Ah, 1);
        SB0;
        READ_B(b_hi, Bh, 1);
        asm volatile("s_waitcnt lgkmcnt(12)" ::: "memory");
        SB0;
        MFMA_Q(0, 0, a_lo, b_lo);
        asm volatile("s_waitcnt lgkmcnt(4)" ::: "memory");
        SB0;
        MFMA_Q(1, 0, a_hi, b_lo);
        asm volatile("s_waitcnt lgkmcnt(0)" ::: "memory");
        SB0;
        MFMA_Q(0, 1, a_lo, b_hi);
        MFMA_Q(1, 1, a_hi, b_hi);
        asm volatile("s_waitcnt vmcnt(0)" ::: "memory");
        __builtin_amdgcn_s_barrier();
        SB0;
    }
}

// ---------------- pv variant: per-row fp16 A-scaling from LDS table --------
__device__ __forceinline__ void gemm256_core_pv(const _Float16* A, long lda,
                                                const _Float16* B, long ldb,
                                                int K, floatx4 acc[8][4],
                                                _Float16* lds, const float* scl) {
    GEMM_PRELUDE
    half8 a_lo[4][2], a_hi[4][2], b_lo[2][2], b_hi[2][2];
    STAGE(0, 0);
    asm volatile("s_waitcnt vmcnt(0)" ::: "memory");
    __builtin_amdgcn_s_barrier();
    SB0;
#pragma unroll 1
    for (int t = 0; t < NT; ++t) {
        const int buf = t & 1;
        if (t + 1 < NT) { STAGE(buf ^ 1, t + 1); }
        const _Float16* Ah = lds + buf * 32768 + wr * 8192;
        const _Float16* Bh = lds + buf * 32768 + 16384 + (wc >> 1) * 8192;
        const float* srow = scl + (t >> 2) * 256 + wr * 128 + rsel;
        float s_lo[4], s_hi[4];
#pragma unroll
        for (int mi = 0; mi < 4; ++mi) s_lo[mi] = srow[mi * 16];
#pragma unroll
        for (int mi = 0; mi < 4; ++mi) s_hi[mi] = srow[64 + mi * 16];
        SB0;
        READ_A(a_lo, Ah, 0);
        READ_B(b_lo, Bh, 0);
        SB0;
        READ_A(a_hi, Ah, 1);
        SB0;
        READ_B(b_hi, Bh, 1);
        asm volatile("s_waitcnt lgkmcnt(12)" ::: "memory");
        SB0;
#pragma unroll
        for (int mi = 0; mi < 4; ++mi) {
            const _Float16 h = (_Float16)s_lo[mi];
            a_lo[mi][0] = a_lo[mi][0] * h;
            a_lo[mi][1] = a_lo[mi][1] * h;
        }
        MFMA_Q(0, 0, a_lo, b_lo);
        asm volatile("s_waitcnt lgkmcnt(4)" ::: "memory");
        SB0;
#pragma unroll
        for (int mi = 0; mi < 4; ++mi) {
            const _Float16 h = (_Float16)s_hi[mi];
            a_hi[mi][0] = a_hi[mi][0] * h;
            a_hi[mi][1] = a_hi[mi][1] * h;
        }
        MFMA_Q(1, 0, a_hi, b_lo);
        asm volatile("s_waitcnt lgkmcnt(0)" ::: "memory");
        SB0;
        MFMA_Q(0, 1, a_lo, b_hi);
        MFMA_Q(1, 1, a_hi, b_hi);
        asm volatile("s_waitcnt vmcnt(0)" ::: "memory");
        __builtin_amdgcn_s_barrier();
        SB0;
    }
}

__device__ __forceinline__ void zero_acc8(floatx4 acc[8][4]) {
    const floatx4 z = {0.f, 0.f, 0.f, 0.f};
#pragma unroll
    for (int m = 0; m < 8; ++m)
#pragma unroll
        for (int n = 0; n < 4; ++n) acc[m][n] = z;
}

// ---------------- kernels ----------------

// merged prep: blocks [0,16384) build X fp16; [16384,20480) convert weights.
__global__ __launch_bounds__(256) void prep_kernel(const float* e1, const float* e2,
                                                   const float* e3, const float* Wq,
                                                   const float* Wk, const float* Wv,
                                                   const float* Wf, _Float16* X,
                                                   _Float16* Wdst) {
    const int bid = blockIdx.x;
    if (bid < 16384) {
        long i = ((long)bid * 256 + threadIdx.x) * 4;
        int m = (int)(i >> 10);
        int c = (int)(i & 1023);
        const float* src;
        if (c < 256)      src = e1 + (long)m * 256 + c;
        else if (c < 512) src = e2 + (long)m * 256 + (c - 256);
        else              src = e3 + (long)m * 512 + (c - 512);
        float4 f = *(const float4*)src;
        half4v h;
        h[0] = (_Float16)f.x; h[1] = (_Float16)f.y;
        h[2] = (_Float16)f.z; h[3] = (_Float16)f.w;
        *(half4v*)&X[i] = h;
    } else {
        long i = ((long)(bid - 16384) * 256 + threadIdx.x) * 4;
        int which = (int)(i >> 20);
        long off = i & 1048575;
        const float* w = which == 0 ? Wq : which == 1 ? Wk : which == 2 ? Wv : Wf;
        float4 f = *(const float4*)(w + off);
        half4v h;
        h[0] = (_Float16)f.x; h[1] = (_Float16)f.y;
        h[2] = (_Float16)f.z; h[3] = (_Float16)f.w;
        *(half4v*)&Wdst[i] = h;
    }
}

// QKV projection: z=0 -> q, z=1 -> k; z=2 -> vT via LDS transpose.
__global__ __launch_bounds__(512, 2) void qkv_kernel(const _Float16* X, const _Float16* W,
                                                     const float* bq, const float* bk,
                                                     const float* bv, _Float16* q,
                                                     _Float16* k, _Float16* vT) {
    extern __shared__ _Float16 lds[];
    const int m0 = blockIdx.x * 256;
    const int n0 = blockIdx.y * 256;
    const int z  = blockIdx.z;
    floatx4 acc[8][4];
    zero_acc8(acc);
    gemm256_core(X + (long)m0 * 1024, 1024,
                 W + (long)z * 1048576 + (long)n0 * 1024, 1024, 1024, acc, lds);

    const float* bias = (z == 0) ? bq : (z == 1) ? bk : bv;
    const int lane = threadIdx.x & 63;
    const int w = threadIdx.x >> 6;
    const int wr = w >> 2, wc = w & 3;
    const int rsel = lane & 15, gsel = lane >> 4;

    if (z == 2) {
        const int rb = wr * 128 + gsel * 4;
        const int cb = wc * 64 + rsel;
#pragma unroll
        for (int mI = 0; mI < 8; ++mI) {
#pragma unroll
            for (int nI = 0; nI < 4; ++nI) {
                const int c = cb + nI * 16;
                const int r = rb + mI * 16;
                const float bb = bias[n0 + c];
                half4v vv;
#pragma unroll
                for (int j = 0; j < 4; ++j) vv[j] = (_Float16)(acc[mI][nI][j] + bb);
                *(half4v*)&lds[c * 256 + (r ^ ((c & 7) << 3))] = vv;
            }
        }
        __syncthreads();
#pragma unroll
        for (int it = 0; it < 16; ++it) {
            const int idx = it * 512 + threadIdx.x;  // 0..8191
            const int c = idx >> 5;
            const int mc = idx & 31;
            half8 v = *(const half8*)&lds[c * 256 + ((mc * 8) ^ ((c & 7) << 3))];
            *(half8*)&vT[(long)(n0 + c) * 16384 + m0 + mc * 8] = v;
        }
    } else {
        _Float16* dst = (z == 0) ? q : k;
        const int r0 = m0 + wr * 128 + gsel * 4;
        const int c0 = n0 + wc * 64 + rsel;
#pragma unroll
        for (int mI = 0; mI < 8; ++mI) {
#pragma unroll
            for (int nI = 0; nI < 4; ++nI) {
                const int r = r0 + mI * 16;
                const int c = c0 + nI * 16;
                const float bb = bias[c];
#pragma unroll
                for (int j = 0; j < 4; ++j)
                    dst[(long)(r + j) * 1024 + c] = (_Float16)(acc[mI][nI][j] + bb);
            }
        }
    }
}

// scores + partial softmax, epilogue v4: shfl-free, scalar-LDS-read-free.
// LDS after GEMM: esb fp16[128][256] @0 (64KB, two passes); redp fp32[256][68]
// @byte 65536 (69.6KB); rowmax fp32[256] @byte 135168. Cap 136192.
// P1 max-partials(LDS w) | P2 256-thr fold | P3 exp-in-reg + sum-partials +
// esb half0 | P4 fold sums -> coalesced tmax/tsum + P6a vector store half0 |
// P5b esb half1 | P6b store half1.
__global__ __launch_bounds__(512, 2) void scores_kernel(const _Float16* qh,
                                                        const _Float16* kh,
                                                        _Float16* es, float* tmax,
                                                        float* tsum) {
    extern __shared__ _Float16 lds[];
    const int b = blockIdx.x;
    const int m0 = (blockIdx.y >> 3) * 256;
    const int tile = blockIdx.y & 7;
    const int n0 = tile * 256;
    floatx4 acc[8][4];
    zero_acc8(acc);
    gemm256_core(qh + ((long)b * 2048 + m0) * 1024, 1024,
                 kh + ((long)b * 2048 + n0) * 1024, 1024, 1024, acc, lds);

    const int lane = threadIdx.x & 63;
    const int w = threadIdx.x >> 6;
    const int wr = w >> 2, wc = w & 3;
    const int rsel = lane & 15, gsel = lane >> 4;
    const int tid = threadIdx.x;
    float* redp   = (float*)(lds + 32768);  // [256][68] fp32
    float* rowmax = (float*)(lds + 67584);  // [256] fp32
    const int slot = wc * 16 + rsel;

    // ---- P1: n-folded max partials -> redp[row][wc*16+rsel]
#pragma unroll
    for (int m = 0; m < 8; ++m) {
#pragma unroll
        for (int j = 0; j < 4; ++j) {
            const int row = wr * 128 + m * 16 + gsel * 4 + j;
            float v = acc[m][0][j];
#pragma unroll
            for (int n = 1; n < 4; ++n) v = fmaxf(v, acc[m][n][j]);
            redp[row * 68 + slot] = v;
        }
    }
    __syncthreads();

    // ---- P2: fold 64 partials/row -> rowmax (256 threads, float4 reads)
    if (tid < 256) {
        const float* rr = redp + tid * 68;
        float mv = -1e30f;
#pragma unroll
        for (int q4 = 0; q4 < 16; ++q4) {
            float4 f = ((const float4*)rr)[q4];
            mv = fmaxf(mv, fmaxf(fmaxf(f.x, f.y), fmaxf(f.z, f.w)));
        }
        rowmax[tid] = mv;
    }
    __syncthreads();

    // ---- P3: exp in regs, sum partials -> redp (reuse), esb half0 write
#pragma unroll
    for (int m = 0; m < 8; ++m) {
#pragma unroll
        for (int j = 0; j < 4; ++j) {
            const int row = wr * 128 + m * 16 + gsel * 4 + j;
            const float mxv = rowmax[row];
            float s = 0.f;
#pragma unroll
            for (int n = 0; n < 4; ++n) {
                float e = __expf(acc[m][n][j] - mxv);
                acc[m][n][j] = e;
                s += e;
            }
            redp[row * 68 + slot] = s;
        }
    }
    // esb half0: acc m 0..3 -> local rows lr = wr*64 + m*16 + gsel*4 + j
#pragma unroll
    for (int m = 0; m < 4; ++m) {
#pragma unroll
        for (int j = 0; j < 4; ++j) {
            const int lr = wr * 64 + m * 16 + gsel * 4 + j;
            const int g = lr & 7;
#pragma unroll
            for (int n = 0; n < 4; ++n) {
                const int c = wc * 64 + n * 16 + rsel;
                lds[lr * 256 + (c ^ (g << 3))] = (_Float16)acc[m][n][j];
            }
        }
    }
    __syncthreads();

    // ---- P4: fold sum partials -> coalesced global tmax/tsum
    if (tid < 256) {
        const float* rr = redp + tid * 68;
        float sv = 0.f;
#pragma unroll
        for (int q4 = 0; q4 < 16; ++q4) {
            float4 f = ((const float4*)rr)[q4];
            sv += f.x + f.y + f.z + f.w;
        }
        const long base = ((long)b * 8 + tile) * 2048 + m0;
        tmax[base + tid] = rowmax[tid];
        tsum[base + tid] = sv;
    }
    // ---- P6a: vector readback + coalesced es store, half0 rows
    const long rbase = (long)b * 2048 * 2048;
#pragma unroll
    for (int it = 0; it < 8; ++it) {
        const int idx = it * 512 + tid;  // 0..4095
        const int lr = idx >> 5;         // 0..127
        const int chunk = idx & 31;
        half8 v = *(const half8*)&lds[lr * 256 + ((chunk ^ (lr & 7)) * 8)];
        const int rg = (lr & 63) + ((lr >> 6) << 7);  // rows 0-63,128-191
        *(half8*)&es[rbase + (long)(m0 + rg) * 2048 + n0 + chunk * 8] = v;
    }
    __syncthreads();

    // ---- P5b: esb half1 from acc m 4..7
#pragma unroll
    for (int m = 4; m < 8; ++m) {
#pragma unroll
        for (int j = 0; j < 4; ++j) {
            const int lr = wr * 64 + (m - 4) * 16 + gsel * 4 + j;
            const int g = lr & 7;
#pragma unroll
            for (int n = 0; n < 4; ++n) {
                const int c = wc * 64 + n * 16 + rsel;
                lds[lr * 256 + (c ^ (g << 3))] = (_Float16)acc[m][n][j];
            }
        }
    }
    __syncthreads();
    // ---- P6b: store half1 rows (64-127, 192-255)
#pragma unroll
    for (int it = 0; it < 8; ++it) {
        const int idx = it * 512 + tid;
        const int lr = idx >> 5;
        const int chunk = idx & 31;
        half8 v = *(const half8*)&lds[lr * 256 + ((chunk ^ (lr & 7)) * 8)];
        const int rg = 64 + (lr & 63) + ((lr >> 6) << 7);
        *(half8*)&es[rbase + (long)(m0 + rg) * 2048 + n0 + chunk * 8] = v;
    }
}

// weighted[b] = (es * scale)[b] @ v[b] via vT; scale computed in prologue
// from tmax/tsum (sm_reduce fused). fp16 out [16384][1024].
__global__ __launch_bounds__(512, 2) void pv_kernel(const _Float16* es,
                                                    const _Float16* vT,
                                                    const float* tmax,
                                                    const float* tsum,
                                                    _Float16* wt) {
    extern __shared__ _Float16 lds[];
    const int batch = blockIdx.x;
    const int m0 = (blockIdx.y >> 2) * 256;
    const int n0 = (blockIdx.y & 3) * 256;
    float* scl = (float*)(lds + 65536);  // [8][256] after the 128KB dbuf
    if (threadIdx.x < 256) {
        const int row = m0 + threadIdx.x;
        float m[8];
        float mg = -1e30f;
#pragma unroll
        for (int t = 0; t < 8; ++t) {
            m[t] = tmax[((long)batch * 8 + t) * 2048 + row];
            mg = fmaxf(mg, m[t]);
        }
        float Z = 0.f;
#pragma unroll
        for (int t = 0; t < 8; ++t)
            Z += tsum[((long)batch * 8 + t) * 2048 + row] * __expf(m[t] - mg);
        const float inv = 1.0f / Z;
#pragma unroll
        for (int t = 0; t < 8; ++t)
            scl[t * 256 + threadIdx.x] = __expf(m[t] - mg) * inv;
    }
    __syncthreads();
    floatx4 acc[8][4];
    zero_acc8(acc);
    gemm256_core_pv(es + ((long)batch * 2048 + m0) * 2048, 2048,
                    vT + (long)n0 * 16384 + (long)batch * 2048, 16384, 2048, acc,
                    lds, scl);

    const int lane = threadIdx.x & 63;
    const int w = threadIdx.x >> 6;
    const int wr = w >> 2, wc = w & 3;
    const int r0 = wr * 128 + (lane >> 4) * 4;
    const int c0 = n0 + wc * 64 + (lane & 15);
#pragma unroll
    for (int m = 0; m < 8; ++m) {
#pragma unroll
        for (int n = 0; n < 4; ++n) {
            const int r = r0 + m * 16;
            const int c = c0 + n * 16;
#pragma unroll
            for (int j = 0; j < 4; ++j)
                wt[((long)batch * 2048 + m0 + r + j) * 1024 + c] =
                    (_Float16)acc[m][n][j];
        }
    }
}

// out = leakyrelu(weighted @ Wf^T + bf), fp32 out.
__global__ __launch_bounds__(512, 2) void out_kernel(const _Float16* wt, const _Float16* Wf,
                                                     const float* bf_, float* out) {
    extern __shared__ _Float16 lds[];
    const int m0 = blockIdx.x * 256;
    const int n0 = blockIdx.y * 256;
    floatx4 acc[8][4];
    zero_acc8(acc);
    gemm256_core(wt + (long)m0 * 1024, 1024, Wf + (long)n0 * 1024, 1024, 1024, acc, lds);

    const int lane = threadIdx.x & 63;
    const int w = threadIdx.x >> 6;
    const int wr = w >> 2, wc = w & 3;
    const int r0 = m0 + wr * 128 + (lane >> 4) * 4;
    const int c0 = n0 + wc * 64 + (lane & 15);
#pragma unroll
    for (int m = 0; m < 8; ++m) {
#pragma unroll
        for (int n = 0; n < 4; ++n) {
            const int r = r0 + m * 16;
            const int c = c0 + n * 16;
            const float bb = bf_[c];
#pragma unroll
            for (int j = 0; j < 4; ++j) {
                float y = acc[m][n][j] + bb;
                y = (y >= 0.f) ? y : 0.2f * y;
                out[(long)(r + j) * 1024 + c] = y;
            }
        }
    }
}

// ---------------- launcher ----------------
extern "C" void kernel_launch(void* const* d_in, const int* in_sizes, int n_in,
                              void* d_out, int out_size, void* d_ws, size_t ws_size,
                              hipStream_t stream) {
    const float* e1 = (const float*)d_in[0];
    const float* e2 = (const float*)d_in[1];
    const float* e3 = (const float*)d_in[2];
    const float* Wq = (const float*)d_in[3];
    const float* bq = (const float*)d_in[4];
    const float* Wk = (const float*)d_in[5];
    const float* bk = (const float*)d_in[6];
    const float* Wv = (const float*)d_in[7];
    const float* bv = (const float*)d_in[8];
    const float* Wf = (const float*)d_in[9];
    const float* bf_ = (const float*)d_in[10];
    float* out = (float*)d_out;

    const int LDS_BYTES = 131072;
    const int LDS_SC = 136192;           // esb 64K (x2 passes) + redp + rowmax
    const int LDS_PV = 131072 + 8192;
    (void)hipFuncSetAttribute((const void*)qkv_kernel,
                              hipFuncAttributeMaxDynamicSharedMemorySize, LDS_BYTES);
    (void)hipFuncSetAttribute((const void*)scores_kernel,
                              hipFuncAttributeMaxDynamicSharedMemorySize, LDS_SC);
    (void)hipFuncSetAttribute((const void*)pv_kernel,
                              hipFuncAttributeMaxDynamicSharedMemorySize, LDS_PV);
    (void)hipFuncSetAttribute((const void*)out_kernel,
                              hipFuncAttributeMaxDynamicSharedMemorySize, LDS_BYTES);

    char* ws = (char*)d_ws;
    const size_t MB = 1024 * 1024;
    _Float16* Xh    = (_Float16*)(ws + 0);        // 32 MiB
    _Float16* Wh    = (_Float16*)(ws + 32 * MB);  // 8 MiB
    _Float16* qh    = (_Float16*)(ws + 40 * MB);  // 32 MiB
    _Float16* kh    = (_Float16*)(ws + 72 * MB);  // 32 MiB
    _Float16* vT    = (_Float16*)(ws + 104 * MB); // 32 MiB [1024][16384]
    _Float16* wt    = (_Float16*)(ws + 136 * MB); // 32 MiB
    _Float16* es    = (_Float16*)(ws + 168 * MB); // 64 MiB [8][2048][2048] fp16
    float* tmax     = (float*)(ws + 232 * MB);              // 512 KiB [8][8][2048]
    float* tsum     = (float*)(ws + 232 * MB + 524288);     // 512 KiB

    prep_kernel<<<20480, 256, 0, stream>>>(e1, e2, e3, Wq, Wk, Wv, Wf, Xh, Wh);
    qkv_kernel<<<dim3(64, 4, 3), 512, LDS_BYTES, stream>>>(Xh, Wh, bq, bk, bv, qh, kh, vT);
    scores_kernel<<<dim3(8, 64), 512, LDS_SC, stream>>>(qh, kh, es, tmax, tsum);
    pv_kernel<<<dim3(8, 32), 512, LDS_PV, stream>>>(es, vT, tmax, tsum, wt);
    out_kernel<<<dim3(64, 4), 512, LDS_BYTES, stream>>>(wt, Wh + 3 * 1048576, bf_, out);
}